// Round 6
// baseline (1653.699 us; speedup 1.0000x reference)
//
#include <hip/hip_runtime.h>
#include <math.h>

#define T_ 32
#define B_ 32
#define S_ 200
#define E_ 512
#define H_ 512
#define V_ 50000
#define G4_ 2048
#define NCH 196   // ceil(50000/256)

using bf16x8 = __attribute__((ext_vector_type(8))) __bf16;
using f32x4  = __attribute__((ext_vector_type(4))) float;

__device__ __forceinline__ float sigf(float x) { return 1.f / (1.f + expf(-x)); }

__device__ __forceinline__ unsigned short f2bf(float v) {
    unsigned int x = __float_as_uint(v);
    return (unsigned short)((x + 0x7FFFu + ((x >> 16) & 1u)) >> 16);
}
__device__ __forceinline__ float bf2f(unsigned short b) {
    return __uint_as_float(((unsigned int)b) << 16);
}

// Coherent (LLC-level) exchange: relaxed agent atomics -> sc-flagged
// global load/store, NO buffer_wbl2/buffer_inv L2 flushes.
__device__ __forceinline__ void g_store(float* p, float v) {
    __hip_atomic_store(p, v, __ATOMIC_RELAXED, __HIP_MEMORY_SCOPE_AGENT);
}
__device__ __forceinline__ float g_load(const float* p) {
    return __hip_atomic_load(p, __ATOMIC_RELAXED, __HIP_MEMORY_SCOPE_AGENT);
}
// 8-byte coherent load (two floats), pipelined like any global load.
__device__ __forceinline__ void g_load2(const float* p, float& a, float& b) {
    unsigned long long u = __hip_atomic_load((const unsigned long long*)p,
                                             __ATOMIC_RELAXED, __HIP_MEMORY_SCOPE_AGENT);
    a = __uint_as_float((unsigned int)u);
    b = __uint_as_float((unsigned int)(u >> 32));
}

// ---------------------------------------------------------------------------
// Fence-free grid barrier (proven round 5). Ordering from __syncthreads'
// vmcnt(0) drain before s_barrier.
// ---------------------------------------------------------------------------
__device__ __forceinline__ void full_sync(int* bar, int ep) {
    __syncthreads();
    if (threadIdx.x == 0) {
        const int g = blockIdx.x & 7;
        int a = __hip_atomic_fetch_add(&bar[g * 32], 1, __ATOMIC_RELAXED, __HIP_MEMORY_SCOPE_AGENT);
        if (a == ep * 32 + 31) {
            int q = __hip_atomic_fetch_add(&bar[256], 1, __ATOMIC_RELAXED, __HIP_MEMORY_SCOPE_AGENT);
            if (q == ep * 8 + 7) {
                #pragma unroll
                for (int i = 0; i < 8; i++)
                    __hip_atomic_store(&bar[288 + i * 32], ep + 1, __ATOMIC_RELAXED, __HIP_MEMORY_SCOPE_AGENT);
            }
        }
        while (__hip_atomic_load(&bar[288 + g * 32], __ATOMIC_RELAXED, __HIP_MEMORY_SCOPE_AGENT) < ep + 1)
            __builtin_amdgcn_s_sleep(1);
    }
    __syncthreads();
}

__device__ __forceinline__ void sub_sync(int* bar, int bb, int t) {
    __syncthreads();
    if (threadIdx.x == 0) {
        __hip_atomic_fetch_add(&bar[544 + bb * 32], 1, __ATOMIC_RELAXED, __HIP_MEMORY_SCOPE_AGENT);
        while (__hip_atomic_load(&bar[544 + bb * 32], __ATOMIC_RELAXED, __HIP_MEMORY_SCOPE_AGENT) < (t + 1) * 8)
            __builtin_amdgcn_s_sleep(1);
    }
    __syncthreads();
}

// ---------------------------------------------------------------------------
// k_init: xT[k'][b] (1024x32). rows 0..511 att=0, rows 512..1023 last_state^T
// ---------------------------------------------------------------------------
__global__ __launch_bounds__(256) void k_init(const float* __restrict__ last_state,
                                              float* __restrict__ xT) {
    const int f = blockIdx.x * 256 + threadIdx.x;
    xT[f] = 0.f;
    const int k = f >> 5, b = f & 31;
    xT[16384 + f] = last_state[b * 512 + k];
}

// ---------------------------------------------------------------------------
// k_g0: G0[m][j] = emb(tgt_in[m]) . W_ih[j][0:512] + b_ih[j] + b_hh[j]
// ---------------------------------------------------------------------------
__global__ __launch_bounds__(256) void k_g0(const int* __restrict__ tgt_in,
                                            const float* __restrict__ emb,
                                            const float* __restrict__ Wih,
                                            const float* __restrict__ bih,
                                            const float* __restrict__ bhh,
                                            float* __restrict__ G0) {
    __shared__ float a_s[32][66];
    __shared__ float w_s[32][130];
    const int tid = threadIdx.x;
    const int m0 = blockIdx.x * 64, n0 = blockIdx.y * 128;
    const int mq = tid >> 5, nq = tid & 31;
    float acc[8][4] = {};
    for (int k0 = 0; k0 < 512; k0 += 32) {
        {
            const int mm = tid >> 2, kq = tid & 3, kk = kq * 8;
            const float* row = emb + (size_t)tgt_in[m0 + mm] * E_ + k0 + kk;
            float4 v0 = *(const float4*)(row);
            float4 v1 = *(const float4*)(row + 4);
            a_s[kk + 0][mm] = v0.x; a_s[kk + 1][mm] = v0.y;
            a_s[kk + 2][mm] = v0.z; a_s[kk + 3][mm] = v0.w;
            a_s[kk + 4][mm] = v1.x; a_s[kk + 5][mm] = v1.y;
            a_s[kk + 6][mm] = v1.z; a_s[kk + 7][mm] = v1.w;
        }
        {
            const int nn = tid >> 1, kq = tid & 1, kk = kq * 16;
            const float* row = Wih + (size_t)(n0 + nn) * 1024 + k0 + kk;
            #pragma unroll
            for (int u = 0; u < 4; u++) {
                float4 v = *(const float4*)(row + u * 4);
                w_s[kk + u * 4 + 0][nn] = v.x; w_s[kk + u * 4 + 1][nn] = v.y;
                w_s[kk + u * 4 + 2][nn] = v.z; w_s[kk + u * 4 + 3][nn] = v.w;
            }
        }
        __syncthreads();
        for (int k = 0; k < 32; k++) {
            float a[8], wv[4];
            #pragma unroll
            for (int i = 0; i < 8; i++) a[i] = a_s[k][mq + 8 * i];
            #pragma unroll
            for (int p = 0; p < 4; p++) wv[p] = w_s[k][nq + 32 * p];
            #pragma unroll
            for (int i = 0; i < 8; i++)
                #pragma unroll
                for (int p = 0; p < 4; p++) acc[i][p] += a[i] * wv[p];
        }
        __syncthreads();
    }
    #pragma unroll
    for (int i = 0; i < 8; i++) {
        const int m = m0 + mq + 8 * i;
        #pragma unroll
        for (int p = 0; p < 4; p++) {
            const int n = n0 + nq + 32 * p;
            G0[(size_t)m * G4_ + n] = acc[i][p] + bih[n] + bhh[n];
        }
    }
}

// ---------------------------------------------------------------------------
// k_u: U[b,s,j] = src[b,s,:] . W_attn[j, 0:512]
// ---------------------------------------------------------------------------
__global__ __launch_bounds__(256) void k_u(const float* __restrict__ src,
                                           const float* __restrict__ Wattn,
                                           float* __restrict__ U) {
    __shared__ float a_s[32][66];
    __shared__ float w_s[32][130];
    const int tid = threadIdx.x;
    const int m0 = blockIdx.x * 64, n0 = blockIdx.y * 128;
    const int mq = tid >> 5, nq = tid & 31;
    float acc[8][4] = {};
    for (int k0 = 0; k0 < 512; k0 += 32) {
        {
            const int mm = tid >> 2, kq = tid & 3, kk = kq * 8;
            const float* row = src + (size_t)(m0 + mm) * 512 + k0 + kk;
            float4 v0 = *(const float4*)(row);
            float4 v1 = *(const float4*)(row + 4);
            a_s[kk + 0][mm] = v0.x; a_s[kk + 1][mm] = v0.y;
            a_s[kk + 2][mm] = v0.z; a_s[kk + 3][mm] = v0.w;
            a_s[kk + 4][mm] = v1.x; a_s[kk + 5][mm] = v1.y;
            a_s[kk + 6][mm] = v1.z; a_s[kk + 7][mm] = v1.w;
        }
        {
            const int nn = tid >> 1, kq = tid & 1, kk = kq * 16;
            const float* row = Wattn + (size_t)(n0 + nn) * 1024 + k0 + kk;
            #pragma unroll
            for (int u = 0; u < 4; u++) {
                float4 v = *(const float4*)(row + u * 4);
                w_s[kk + u * 4 + 0][nn] = v.x; w_s[kk + u * 4 + 1][nn] = v.y;
                w_s[kk + u * 4 + 2][nn] = v.z; w_s[kk + u * 4 + 3][nn] = v.w;
            }
        }
        __syncthreads();
        for (int k = 0; k < 32; k++) {
            float a[8], wv[4];
            #pragma unroll
            for (int i = 0; i < 8; i++) a[i] = a_s[k][mq + 8 * i];
            #pragma unroll
            for (int p = 0; p < 4; p++) wv[p] = w_s[k][nq + 32 * p];
            #pragma unroll
            for (int i = 0; i < 8; i++)
                #pragma unroll
                for (int p = 0; p < 4; p++) acc[i][p] += a[i] * wv[p];
        }
        __syncthreads();
    }
    #pragma unroll
    for (int i = 0; i < 8; i++) {
        const int m = m0 + mq + 8 * i;
        #pragma unroll
        for (int p = 0; p < 4; p++)
            U[(size_t)m * 512 + n0 + nq + 32 * p] = acc[i][p];
    }
}

// ---------------------------------------------------------------------------
// k_tr: WaRT[k][j] = W_attn[j][512+k]
// ---------------------------------------------------------------------------
__global__ __launch_bounds__(256) void k_tr(const float* __restrict__ Wattn,
                                            float* __restrict__ WaRT) {
    __shared__ float t_s[32][33];
    const int tid = threadIdx.x;
    const int bx = blockIdx.x, by = blockIdx.y;
    {
        const int jj = tid >> 3, kq = (tid & 7) * 4;
        float4 v = *(const float4*)(Wattn + (size_t)(by * 32 + jj) * 1024 + 512 + bx * 32 + kq);
        t_s[jj][kq + 0] = v.x; t_s[jj][kq + 1] = v.y;
        t_s[jj][kq + 2] = v.z; t_s[jj][kq + 3] = v.w;
    }
    __syncthreads();
    {
        const int kk = tid >> 3, jq = (tid & 7) * 4;
        float4 w;
        w.x = t_s[jq + 0][kk]; w.y = t_s[jq + 1][kk];
        w.z = t_s[jq + 2][kk]; w.w = t_s[jq + 3][kk];
        *(float4*)(WaRT + (size_t)(bx * 32 + kk) * 512 + by * 32 + jq) = w;
    }
}

// ---------------------------------------------------------------------------
// Persistent scan, fence-free. 256 blocks x 256 threads.
// Phase A now loads x fragments DIRECTLY from xT (coherent 8B loads) into
// registers: no LDS staging, no per-chunk __syncthreads.
// ---------------------------------------------------------------------------
__global__ __launch_bounds__(256) void k_scan(const float* __restrict__ G0,
                                              const float* __restrict__ U,
                                              const float* __restrict__ WaRT,
                                              const float* __restrict__ Wih,
                                              const float* __restrict__ Whh,
                                              const float* __restrict__ src,
                                              const int* __restrict__ lens,
                                              const float* __restrict__ last_cell,
                                              float* __restrict__ gbuf,
                                              float* __restrict__ xT,
                                              float* __restrict__ scb,
                                              float* __restrict__ h_hist,
                                              float* __restrict__ att_hist,
                                              int* __restrict__ bar) {
    __shared__ float Wl[8 * 1024];     // 32 KB gate weight rows [r][k']
    __shared__ float Ul[200 * 64];     // 51.2 KB U slice
    __shared__ float red_s[1024];
    __shared__ float h_s[512];
    __shared__ float al[256];
    __shared__ float pr[256];

    const int blk = blockIdx.x, tid = threadIdx.x;
    const int j0 = blk * 8;
    const int bb = blk & 31, p = blk >> 5;

    for (int f = tid; f < 2048; f += 256) {
        const int row = f >> 8, k = (f & 255) * 4;
        float4 v;
        if (k < 512) v = *(const float4*)(Wih + (size_t)(j0 + row) * 1024 + 512 + k);
        else         v = *(const float4*)(Whh + (size_t)(j0 + row) * 512 + (k - 512));
        *(float4*)&Wl[row * 1024 + k] = v;
    }
    for (int f = tid; f < 3200; f += 256) {
        const int s = f >> 4, q = (f & 15) * 4;
        *(float4*)&Ul[s * 64 + q] = *(const float4*)(U + ((size_t)bb * S_ + s) * 512 + p * 64 + q);
    }
    float creg0 = last_cell[bb * 512 + tid];
    float creg1 = last_cell[bb * 512 + 256 + tid];
    __syncthreads();

    const int wid = tid >> 6, lane = tid & 63;
    const int kgl = lane >> 2, bg = lane & 3;
    const int q64 = wid * 16 + kgl;                 // 0..63
    const int len = lens[bb];

    for (int t = 0; t < T_; t++) {
        // ---------------- Phase A: gates (direct coherent loads) ----------
        {
            float acc[8][8];
            #pragma unroll
            for (int r = 0; r < 8; r++)
                #pragma unroll
                for (int bi = 0; bi < 8; bi++) acc[r][bi] = 0.f;

            #pragma unroll
            for (int c = 0; c < 4; c++) {
                const int kb = c * 256 + q64 * 4;
                float xv[4][8];
                #pragma unroll
                for (int i = 0; i < 4; i++) {
                    const float* rp = xT + (size_t)(kb + i) * 32 + bg * 8;
                    g_load2(rp + 0, xv[i][0], xv[i][1]);
                    g_load2(rp + 2, xv[i][2], xv[i][3]);
                    g_load2(rp + 4, xv[i][4], xv[i][5]);
                    g_load2(rp + 6, xv[i][6], xv[i][7]);
                }
                float4 wf[8];
                #pragma unroll
                for (int r = 0; r < 8; r++)
                    wf[r] = *(const float4*)&Wl[r * 1024 + kb];
                #pragma unroll
                for (int bi = 0; bi < 8; bi++)
                    #pragma unroll
                    for (int r = 0; r < 8; r++)
                        acc[r][bi] += xv[0][bi] * wf[r].x + xv[1][bi] * wf[r].y
                                    + xv[2][bi] * wf[r].z + xv[3][bi] * wf[r].w;
            }
            #pragma unroll
            for (int m = 4; m < 64; m <<= 1)
                #pragma unroll
                for (int r = 0; r < 8; r++)
                    #pragma unroll
                    for (int bi = 0; bi < 8; bi++)
                        acc[r][bi] += __shfl_xor(acc[r][bi], m);
            if (kgl == 0) {
                #pragma unroll
                for (int r = 0; r < 8; r++)
                    #pragma unroll
                    for (int bi = 0; bi < 8; bi++)
                        red_s[wid * 256 + r * 32 + bg * 8 + bi] = acc[r][bi];
            }
            __syncthreads();
            {
                const int r = tid >> 5, b2 = tid & 31;
                g_store(&gbuf[(size_t)(j0 + r) * 32 + b2],
                        red_s[tid] + red_s[256 + tid] + red_s[512 + tid] + red_s[768 + tid]);
            }
        }
        full_sync(bar, 2 * t);

        // ---------------- Phase B: pointwise + scores ----------------
        {
            const size_t g0b = ((size_t)t * B_ + bb) * G4_;
            {
                const int u = tid;
                const float gi = g_load(&gbuf[(size_t)u * 32 + bb])          + G0[g0b + u];
                const float gf = g_load(&gbuf[(size_t)(512 + u) * 32 + bb])  + G0[g0b + 512 + u];
                const float gg = g_load(&gbuf[(size_t)(1024 + u) * 32 + bb]) + G0[g0b + 1024 + u];
                const float go = g_load(&gbuf[(size_t)(1536 + u) * 32 + bb]) + G0[g0b + 1536 + u];
                const float cn = sigf(gf) * creg0 + sigf(gi) * tanhf(gg);
                const float hn = sigf(go) * tanhf(cn);
                creg0 = cn;
                h_s[u] = hn;
                if (p == 0) h_hist[((size_t)t * B_ + bb) * 512 + u] = hn;
            }
            {
                const int u = tid + 256;
                const float gi = g_load(&gbuf[(size_t)u * 32 + bb])          + G0[g0b + u];
                const float gf = g_load(&gbuf[(size_t)(512 + u) * 32 + bb])  + G0[g0b + 512 + u];
                const float gg = g_load(&gbuf[(size_t)(1024 + u) * 32 + bb]) + G0[g0b + 1024 + u];
                const float go = g_load(&gbuf[(size_t)(1536 + u) * 32 + bb]) + G0[g0b + 1536 + u];
                const float cn = sigf(gf) * creg1 + sigf(gi) * tanhf(gg);
                const float hn = sigf(go) * tanhf(cn);
                creg1 = cn;
                h_s[u] = hn;
                if (p == 0) h_hist[((size_t)t * B_ + bb) * 512 + u] = hn;
            }
            __syncthreads();
            if (tid < 64)
                g_store(&xT[(512 + p * 64 + tid) * 32 + bb], h_s[p * 64 + tid]);
            for (int i = wid; i < 25; i += 4) {
                const int s = p * 25 + i;
                const float* sr = src + ((size_t)bb * S_ + s) * 512;
                const float4 x0 = *(const float4*)(sr + lane * 4);
                const float4 x1 = *(const float4*)(sr + 256 + lane * 4);
                const float4 h0 = *(const float4*)(&h_s[lane * 4]);
                const float4 h1 = *(const float4*)(&h_s[256 + lane * 4]);
                float a = x0.x * h0.x + x0.y * h0.y + x0.z * h0.z + x0.w * h0.w
                        + x1.x * h1.x + x1.y * h1.y + x1.z * h1.z + x1.w * h1.w;
                #pragma unroll
                for (int mk = 1; mk < 64; mk <<= 1) a += __shfl_xor(a, mk);
                if (lane == 0) g_store(&scb[bb * 256 + s], (s < len) ? a : -INFINITY);
            }
        }
        sub_sync(bar, bb, t);

        // ---------------- Phase C: softmax + att slice ----------------
        {
            if (tid < 64) {
                const float v0 = g_load(&scb[bb * 256 + tid]);
                const float v1 = g_load(&scb[bb * 256 + 64 + tid]);
                const float v2 = g_load(&scb[bb * 256 + 128 + tid]);
                const float v3 = (tid < 8) ? g_load(&scb[bb * 256 + 192 + tid]) : -INFINITY;
                float m = fmaxf(fmaxf(v0, v1), fmaxf(v2, v3));
                #pragma unroll
                for (int mk = 1; mk < 64; mk <<= 1) m = fmaxf(m, __shfl_xor(m, mk));
                const float e0 = expf(v0 - m), e1 = expf(v1 - m), e2 = expf(v2 - m);
                const float e3 = (tid < 8) ? expf(v3 - m) : 0.f;
                float sum = (e0 + e1) + (e2 + e3);
                #pragma unroll
                for (int mk = 1; mk < 64; mk <<= 1) sum += __shfl_xor(sum, mk);
                const float inv = 1.f / sum;
                al[tid] = e0 * inv; al[64 + tid] = e1 * inv; al[128 + tid] = e2 * inv;
                if (tid < 8) al[192 + tid] = e3 * inv;
            }
            __syncthreads();
            const int jl = tid & 63, sg = tid >> 6;
            float u0 = 0.f, u1 = 0.f;
            for (int s = sg * 50; s < sg * 50 + 50; s += 2) {
                u0 += al[s] * Ul[s * 64 + jl];
                u1 += al[s + 1] * Ul[(s + 1) * 64 + jl];
            }
            const float* wc0 = WaRT + (size_t)(sg * 128) * 512 + p * 64 + jl;
            float c0 = 0.f, c1 = 0.f, c2 = 0.f, c3 = 0.f;
            #pragma unroll 8
            for (int kk = 0; kk < 128; kk += 4) {
                const float* hp = &h_s[sg * 128 + kk];
                c0 += hp[0] * wc0[(size_t)(kk + 0) * 512];
                c1 += hp[1] * wc0[(size_t)(kk + 1) * 512];
                c2 += hp[2] * wc0[(size_t)(kk + 2) * 512];
                c3 += hp[3] * wc0[(size_t)(kk + 3) * 512];
            }
            pr[sg * 64 + jl] = (u0 + u1) + ((c0 + c1) + (c2 + c3));
            __syncthreads();
            if (tid < 64) {
                const float tot = pr[tid] + pr[64 + tid] + pr[128 + tid] + pr[192 + tid];
                const float a = tanhf(tot);
                g_store(&xT[(p * 64 + tid) * 32 + bb], a);
                att_hist[((size_t)t * B_ + bb) * 512 + p * 64 + tid] = a;
            }
        }
        full_sync(bar, 2 * t + 1);
    }
}

// ---------------------------------------------------------------------------
// k_dec: dh/dl = bf16-split( tanh([emb|h_hist|att_hist] @ Wgen^T + bgen) )
// ---------------------------------------------------------------------------
__global__ __launch_bounds__(256) void k_dec(const int* __restrict__ tgt_in,
                                             const float* __restrict__ emb,
                                             const float* __restrict__ h_hist,
                                             const float* __restrict__ att_hist,
                                             const float* __restrict__ Wgen,
                                             const float* __restrict__ bgen,
                                             unsigned short* __restrict__ dh,
                                             unsigned short* __restrict__ dl) {
    __shared__ float a_s[32][66];
    __shared__ float w_s[32][130];
    const int tid = threadIdx.x;
    const int m0 = blockIdx.x * 64, n0 = blockIdx.y * 128;
    const int mq = tid >> 5, nq = tid & 31;
    float acc[8][4] = {};
    for (int k0 = 0; k0 < 1536; k0 += 32) {
        {
            const int mm = tid >> 2, kq = tid & 3, kk = kq * 8;
            const int m = m0 + mm;
            const float* row;
            if (k0 < 512)       row = emb + (size_t)tgt_in[m] * E_ + k0;
            else if (k0 < 1024) row = h_hist + (size_t)m * 512 + (k0 - 512);
            else                row = att_hist + (size_t)m * 512 + (k0 - 1024);
            row += kk;
            float4 v0 = *(const float4*)(row);
            float4 v1 = *(const float4*)(row + 4);
            a_s[kk + 0][mm] = v0.x; a_s[kk + 1][mm] = v0.y;
            a_s[kk + 2][mm] = v0.z; a_s[kk + 3][mm] = v0.w;
            a_s[kk + 4][mm] = v1.x; a_s[kk + 5][mm] = v1.y;
            a_s[kk + 6][mm] = v1.z; a_s[kk + 7][mm] = v1.w;
        }
        {
            const int nn = tid >> 1, kq = tid & 1, kk = kq * 16;
            const float* row = Wgen + (size_t)(n0 + nn) * 1536 + k0 + kk;
            #pragma unroll
            for (int u = 0; u < 4; u++) {
                float4 v = *(const float4*)(row + u * 4);
                w_s[kk + u * 4 + 0][nn] = v.x; w_s[kk + u * 4 + 1][nn] = v.y;
                w_s[kk + u * 4 + 2][nn] = v.z; w_s[kk + u * 4 + 3][nn] = v.w;
            }
        }
        __syncthreads();
        for (int k = 0; k < 32; k++) {
            float a[8], wv[4];
            #pragma unroll
            for (int i = 0; i < 8; i++) a[i] = a_s[k][mq + 8 * i];
            #pragma unroll
            for (int pq = 0; pq < 4; pq++) wv[pq] = w_s[k][nq + 32 * pq];
            #pragma unroll
            for (int i = 0; i < 8; i++)
                #pragma unroll
                for (int pq = 0; pq < 4; pq++) acc[i][pq] += a[i] * wv[pq];
        }
        __syncthreads();
    }
    #pragma unroll
    for (int i = 0; i < 8; i++) {
        const int m = m0 + mq + 8 * i;
        #pragma unroll
        for (int pq = 0; pq < 4; pq++) {
            const int n = n0 + nq + 32 * pq;
            const float v = tanhf(acc[i][pq] + bgen[n]);
            const unsigned short hb = f2bf(v);
            dh[(size_t)m * 512 + n] = hb;
            dl[(size_t)m * 512 + n] = f2bf(v - bf2f(hb));
        }
    }
}

// ---------------------------------------------------------------------------
// k_read: bf16-split MFMA readout. Block 64(M)x256(N), K=512, 4 waves.
// Grid 3200, XCD-grouped: all 16 m-blocks of a chunk land on one XCD so the
// 512 KB Wread chunk is pulled from LLC once per XCD then L2-hit.
// ---------------------------------------------------------------------------
__global__ __launch_bounds__(256) void k_read(const unsigned short* __restrict__ dh,
                                              const unsigned short* __restrict__ dl,
                                              const float* __restrict__ Wread,
                                              const int* __restrict__ tgt_out,
                                              float4* __restrict__ part,
                                              float* __restrict__ tgt_logit) {
    __shared__ __align__(16) unsigned short Bh[4][256][8];
    __shared__ __align__(16) unsigned short Bl[4][256][8];
    __shared__ __align__(16) unsigned short Ah[4][64][8];
    __shared__ __align__(16) unsigned short Alo[4][64][8];
    __shared__ float ep_max[64][2];
    __shared__ int   ep_idx[64][2];
    __shared__ float ep_fin[64];
    __shared__ int   ep_fidx[64];
    __shared__ float ep_sum[64][2];

    const int xcd = blockIdx.x & 7;
    const int idx = blockIdx.x >> 3;
    const int mi  = idx & 15;
    const int group = idx >> 4;         // 0..24
    const int ch = group * 8 + xcd;
    if (ch >= NCH) return;
    const int m0 = mi * 64, n0 = ch * 256;

    const int tid = threadIdx.x;
    const int lane = tid & 63, wid = tid >> 6;
    const int wr = wid >> 1, wc = wid & 1;
    const int l15 = lane & 15, lk = lane >> 4;

    f32x4 acc[2][8];
    #pragma unroll
    for (int mt = 0; mt < 2; mt++)
        #pragma unroll
        for (int nt = 0; nt < 8; nt++) acc[mt][nt] = {0.f, 0.f, 0.f, 0.f};

    for (int kc = 0; kc < 512; kc += 32) {
        {
            const int n = n0 + tid;
            const float* row = Wread + (size_t)n * 512 + kc;
            #pragma unroll
            for (int g = 0; g < 4; g++) {
                uint4 h4, l4;
                if (n < V_) {
                    float4 p0 = *(const float4*)(row + g * 8);
                    float4 p1 = *(const float4*)(row + g * 8 + 4);
                    float v[8] = {p0.x, p0.y, p0.z, p0.w, p1.x, p1.y, p1.z, p1.w};
                    unsigned int hb[8], lb[8];
                    #pragma unroll
                    for (int e = 0; e < 8; e++) {
                        hb[e] = f2bf(v[e]);
                        lb[e] = f2bf(v[e] - bf2f((unsigned short)hb[e]));
                    }
                    h4 = make_uint4(hb[0] | (hb[1] << 16), hb[2] | (hb[3] << 16),
                                    hb[4] | (hb[5] << 16), hb[6] | (hb[7] << 16));
                    l4 = make_uint4(lb[0] | (lb[1] << 16), lb[2] | (lb[3] << 16),
                                    lb[4] | (lb[5] << 16), lb[6] | (lb[7] << 16));
                } else {
                    h4 = make_uint4(0, 0, 0, 0);
                    l4 = make_uint4(0, 0, 0, 0);
                }
                *(uint4*)&Bh[g][tid][0] = h4;
                *(uint4*)&Bl[g][tid][0] = l4;
            }
        }
        {
            const int row = tid >> 2, g = tid & 3;
            *(uint4*)&Ah[g][row][0]  = *(const uint4*)(dh + (size_t)(m0 + row) * 512 + kc + g * 8);
            *(uint4*)&Alo[g][row][0] = *(const uint4*)(dl + (size_t)(m0 + row) * 512 + kc + g * 8);
        }
        __syncthreads();
        {
            bf16x8 afh[2], afl[2];
            #pragma unroll
            for (int mt = 0; mt < 2; mt++) {
                const int r = wr * 32 + mt * 16 + l15;
                afh[mt] = *(const bf16x8*)&Ah[lk][r][0];
                afl[mt] = *(const bf16x8*)&Alo[lk][r][0];
            }
            #pragma unroll
            for (int nt = 0; nt < 8; nt++) {
                const int nn = wc * 128 + nt * 16 + l15;
                bf16x8 bh = *(const bf16x8*)&Bh[lk][nn][0];
                bf16x8 bl = *(const bf16x8*)&Bl[lk][nn][0];
                #pragma unroll
                for (int mt = 0; mt < 2; mt++) {
                    acc[mt][nt] = __builtin_amdgcn_mfma_f32_16x16x32_bf16(afh[mt], bh, acc[mt][nt], 0, 0, 0);
                    acc[mt][nt] = __builtin_amdgcn_mfma_f32_16x16x32_bf16(afl[mt], bh, acc[mt][nt], 0, 0, 0);
                    acc[mt][nt] = __builtin_amdgcn_mfma_f32_16x16x32_bf16(afh[mt], bl, acc[mt][nt], 0, 0, 0);
                }
            }
        }
        __syncthreads();
    }

    #pragma unroll
    for (int mt = 0; mt < 2; mt++)
        #pragma unroll
        for (int reg = 0; reg < 4; reg++) {
            float bv = -INFINITY; int bi = 0x7fffffff;
            #pragma unroll
            for (int nt = 0; nt < 8; nt++) {
                const int n = n0 + wc * 128 + nt * 16 + l15;
                const float v = (n < V_) ? acc[mt][nt][reg] : -INFINITY;
                if (v > bv || (v == bv && n < bi)) { bv = v; bi = n; }
            }
            #pragma unroll
            for (int mk = 1; mk < 16; mk <<= 1) {
                const float ov = __shfl_xor(bv, mk);
                const int oi = __shfl_xor(bi, mk);
                if (ov > bv || (ov == bv && oi < bi)) { bv = ov; bi = oi; }
            }
            if (l15 == 0) {
                const int rl = wr * 32 + mt * 16 + lk * 4 + reg;
                ep_max[rl][wc] = bv; ep_idx[rl][wc] = bi;
            }
        }
    __syncthreads();
    if (tid < 64) {
        const float a = ep_max[tid][0], b = ep_max[tid][1];
        const int ia = ep_idx[tid][0], ib = ep_idx[tid][1];
        const bool tb = (b > a) || (b == a && ib < ia);
        ep_fin[tid] = tb ? b : a; ep_fidx[tid] = tb ? ib : ia;
    }
    __syncthreads();
    #pragma unroll
    for (int mt = 0; mt < 2; mt++)
        #pragma unroll
        for (int reg = 0; reg < 4; reg++) {
            const int rl = wr * 32 + mt * 16 + lk * 4 + reg;
            const float M = ep_fin[rl];
            const int rel = tgt_out[m0 + rl] - n0;
            float se = 0.f;
            #pragma unroll
            for (int nt = 0; nt < 8; nt++) {
                const int nl = wc * 128 + nt * 16 + l15;
                if (n0 + nl < V_) {
                    const float v = acc[mt][nt][reg];
                    se += expf(v - M);
                    if (nl == rel) tgt_logit[m0 + rl] = v;
                }
            }
            #pragma unroll
            for (int mk = 1; mk < 16; mk <<= 1) se += __shfl_xor(se, mk);
            if (l15 == 0) ep_sum[rl][wc] = se;
        }
    __syncthreads();
    if (tid < 64) {
        part[(size_t)(m0 + tid) * NCH + ch] =
            make_float4(ep_fin[tid], ep_sum[tid][0] + ep_sum[tid][1],
                        __int_as_float(ep_fidx[tid]), 0.f);
    }
}

// ---------------------------------------------------------------------------
// k_merge: combine chunk partials -> loss + argmax
// ---------------------------------------------------------------------------
__global__ __launch_bounds__(256) void k_merge(const float4* __restrict__ part,
                                               const float* __restrict__ tgt_logit,
                                               const int* __restrict__ tgt_out,
                                               float* __restrict__ out) {
    const int tid = threadIdx.x;
    const int w = tid >> 6, lane = tid & 63;
    const int row = blockIdx.x * 4 + w;
    float bm = -INFINITY; int bi = 0x7fffffff;
    for (int ch = lane; ch < NCH; ch += 64) {
        const float4 p = part[(size_t)row * NCH + ch];
        const int pi = __float_as_int(p.z);
        if (p.x > bm || (p.x == bm && pi < bi)) { bm = p.x; bi = pi; }
    }
    #pragma unroll
    for (int mk = 1; mk < 64; mk <<= 1) {
        const float ov = __shfl_xor(bm, mk);
        const int oi = __shfl_xor(bi, mk);
        if (ov > bm || (ov == bm && oi < bi)) { bm = ov; bi = oi; }
    }
    float sum = 0.f;
    for (int ch = lane; ch < NCH; ch += 64) {
        const float4 p = part[(size_t)row * NCH + ch];
        sum += p.y * expf(p.x - bm);
    }
    #pragma unroll
    for (int mk = 1; mk < 64; mk <<= 1) sum += __shfl_xor(sum, mk);
    if (lane == 0) {
        const float lse = bm + logf(sum);
        const int tg = tgt_out[row];
        const float loss = (tg != 0) ? (lse - tgt_logit[row]) : 0.f;
        out[row] = loss;
        out[1024 + row] = (float)bi;
    }
}

// ---------------------------------------------------------------------------
extern "C" void kernel_launch(void* const* d_in, const int* in_sizes, int n_in,
                              void* d_out, int out_size, void* d_ws, size_t ws_size,
                              hipStream_t stream) {
    const int* tgt_in = (const int*)d_in[0];
    const int* tgt_out = (const int*)d_in[1];
    const int* src_lens = (const int*)d_in[2];
    const float* src = (const float*)d_in[3];
    const float* last_state = (const float*)d_in[4];
    const float* last_cell = (const float*)d_in[5];
    const float* emb = (const float*)d_in[6];
    const float* Wih = (const float*)d_in[7];
    const float* Whh = (const float*)d_in[8];
    const float* bih = (const float*)d_in[9];
    const float* bhh = (const float*)d_in[10];
    const float* Wattn = (const float*)d_in[11];
    const float* Wgen = (const float*)d_in[12];
    const float* bgen = (const float*)d_in[13];
    const float* Wread = (const float*)d_in[14];
    float* out = (float*)d_out;

    float* ws = (float*)d_ws;
    float* G0       = ws;                    // 2,097,152
    float* U        = G0 + 2097152;          // 3,276,800
    float* WaRT     = U + 3276800;           // 262,144
    unsigned short* dh = (unsigned short*)(WaRT + 262144);  // 524,288 u16
    unsigned short* dl = dh + 524288;                       // 524,288 u16
    float* h_hist   = (float*)(dl + 524288); // 524,288
    float* att_hist = h_hist + 524288;       // 524,288
    float* xT       = att_hist + 524288;     // 32,768
    float* gbuf     = xT + 32768;            // 65,536
    float* scb      = gbuf + 65536;          // 8,192
    float4* part    = (float4*)(scb + 8192); // 200,704 float4
    float* tgtl     = ((float*)part) + 802816; // 1,024
    int* bar        = (int*)(tgtl + 1024);     // 2,048 ints

    hipMemsetAsync(bar, 0, 8192, stream);

    k_init<<<64, 256, 0, stream>>>(last_state, xT);
    k_g0<<<dim3(16, 16), 256, 0, stream>>>(tgt_in, emb, Wih, bih, bhh, G0);
    k_u<<<dim3(100, 4), 256, 0, stream>>>(src, Wattn, U);
    k_tr<<<dim3(16, 16), 256, 0, stream>>>(Wattn, WaRT);

    k_scan<<<256, 256, 0, stream>>>(G0, U, WaRT, Wih, Whh, src, src_lens, last_cell,
                                    gbuf, xT, scb, h_hist, att_hist, bar);

    k_dec<<<dim3(16, 4), 256, 0, stream>>>(tgt_in, emb, h_hist, att_hist, Wgen, bgen, dh, dl);
    k_read<<<3200, 256, 0, stream>>>(dh, dl, Wread, tgt_out, part, tgtl);
    k_merge<<<256, 256, 0, stream>>>(part, tgtl, tgt_out, out);
}

// Round 7
// 1136.317 us; speedup vs baseline: 1.4553x; 1.4553x over previous
//
#include <hip/hip_runtime.h>
#include <math.h>

#define T_ 32
#define B_ 32
#define S_ 200
#define E_ 512
#define H_ 512
#define V_ 50000
#define G4_ 2048
#define NCH 196   // ceil(50000/256)

using bf16x8 = __attribute__((ext_vector_type(8))) __bf16;
using f32x4  = __attribute__((ext_vector_type(4))) float;

__device__ __forceinline__ float sigf(float x) { return 1.f / (1.f + expf(-x)); }

__device__ __forceinline__ unsigned short f2bf(float v) {
    unsigned int x = __float_as_uint(v);
    return (unsigned short)((x + 0x7FFFu + ((x >> 16) & 1u)) >> 16);
}
__device__ __forceinline__ float bf2f(unsigned short b) {
    return __uint_as_float(((unsigned int)b) << 16);
}

// Coherent LLC-level exchange (relaxed agent atomics -> sc1 load/store, no L2 flush)
__device__ __forceinline__ void g_store(float* p, float v) {
    __hip_atomic_store(p, v, __ATOMIC_RELAXED, __HIP_MEMORY_SCOPE_AGENT);
}
__device__ __forceinline__ float g_load(const float* p) {
    return __hip_atomic_load(p, __ATOMIC_RELAXED, __HIP_MEMORY_SCOPE_AGENT);
}

// ---------------------------------------------------------------------------
// Fence-free grid barrier (proven round 5/6).
// ---------------------------------------------------------------------------
__device__ __forceinline__ void full_sync(int* bar, int ep) {
    __syncthreads();
    if (threadIdx.x == 0) {
        const int g = blockIdx.x & 7;
        int a = __hip_atomic_fetch_add(&bar[g * 32], 1, __ATOMIC_RELAXED, __HIP_MEMORY_SCOPE_AGENT);
        if (a == ep * 32 + 31) {
            int q = __hip_atomic_fetch_add(&bar[256], 1, __ATOMIC_RELAXED, __HIP_MEMORY_SCOPE_AGENT);
            if (q == ep * 8 + 7) {
                #pragma unroll
                for (int i = 0; i < 8; i++)
                    __hip_atomic_store(&bar[288 + i * 32], ep + 1, __ATOMIC_RELAXED, __HIP_MEMORY_SCOPE_AGENT);
            }
        }
        while (__hip_atomic_load(&bar[288 + g * 32], __ATOMIC_RELAXED, __HIP_MEMORY_SCOPE_AGENT) < ep + 1)
            __builtin_amdgcn_s_sleep(1);
    }
    __syncthreads();
}

__device__ __forceinline__ void sub_sync(int* bar, int bb, int t) {
    __syncthreads();
    if (threadIdx.x == 0) {
        __hip_atomic_fetch_add(&bar[544 + bb * 32], 1, __ATOMIC_RELAXED, __HIP_MEMORY_SCOPE_AGENT);
        while (__hip_atomic_load(&bar[544 + bb * 32], __ATOMIC_RELAXED, __HIP_MEMORY_SCOPE_AGENT) < (t + 1) * 8)
            __builtin_amdgcn_s_sleep(1);
    }
    __syncthreads();
}

// ---------------------------------------------------------------------------
// k_init: xT rows 0..511 att=0; rows 1024..1535 = last_state^T (h slot 1,
// read by step 0). Rows 512..1023 (slot 0) are written at t=0 before any read.
// ---------------------------------------------------------------------------
__global__ __launch_bounds__(256) void k_init(const float* __restrict__ last_state,
                                              float* __restrict__ xT) {
    const int f = blockIdx.x * 256 + threadIdx.x;   // 0..16383
    xT[f] = 0.f;
    const int k = f >> 5, b = f & 31;
    xT[32768 + f] = last_state[b * 512 + k];
}

// ---------------------------------------------------------------------------
// k_g0: G0T[j][m] = emb(tgt_in[m]) . W_ih[j][0:512] + b_ih[j] + b_hh[j]
// (transposed output for coalesced in-scan reads)
// ---------------------------------------------------------------------------
__global__ __launch_bounds__(256) void k_g0(const int* __restrict__ tgt_in,
                                            const float* __restrict__ emb,
                                            const float* __restrict__ Wih,
                                            const float* __restrict__ bih,
                                            const float* __restrict__ bhh,
                                            float* __restrict__ G0T) {
    __shared__ float a_s[32][66];
    __shared__ float w_s[32][130];
    const int tid = threadIdx.x;
    const int m0 = blockIdx.x * 64, n0 = blockIdx.y * 128;
    const int mq = tid >> 5, nq = tid & 31;
    float acc[8][4] = {};
    for (int k0 = 0; k0 < 512; k0 += 32) {
        {
            const int mm = tid >> 2, kq = tid & 3, kk = kq * 8;
            const float* row = emb + (size_t)tgt_in[m0 + mm] * E_ + k0 + kk;
            float4 v0 = *(const float4*)(row);
            float4 v1 = *(const float4*)(row + 4);
            a_s[kk + 0][mm] = v0.x; a_s[kk + 1][mm] = v0.y;
            a_s[kk + 2][mm] = v0.z; a_s[kk + 3][mm] = v0.w;
            a_s[kk + 4][mm] = v1.x; a_s[kk + 5][mm] = v1.y;
            a_s[kk + 6][mm] = v1.z; a_s[kk + 7][mm] = v1.w;
        }
        {
            const int nn = tid >> 1, kq = tid & 1, kk = kq * 16;
            const float* row = Wih + (size_t)(n0 + nn) * 1024 + k0 + kk;
            #pragma unroll
            for (int u = 0; u < 4; u++) {
                float4 v = *(const float4*)(row + u * 4);
                w_s[kk + u * 4 + 0][nn] = v.x; w_s[kk + u * 4 + 1][nn] = v.y;
                w_s[kk + u * 4 + 2][nn] = v.z; w_s[kk + u * 4 + 3][nn] = v.w;
            }
        }
        __syncthreads();
        for (int k = 0; k < 32; k++) {
            float a[8], wv[4];
            #pragma unroll
            for (int i = 0; i < 8; i++) a[i] = a_s[k][mq + 8 * i];
            #pragma unroll
            for (int p = 0; p < 4; p++) wv[p] = w_s[k][nq + 32 * p];
            #pragma unroll
            for (int i = 0; i < 8; i++)
                #pragma unroll
                for (int p = 0; p < 4; p++) acc[i][p] += a[i] * wv[p];
        }
        __syncthreads();
    }
    #pragma unroll
    for (int i = 0; i < 8; i++) {
        const int m = m0 + mq + 8 * i;
        #pragma unroll
        for (int p = 0; p < 4; p++) {
            const int n = n0 + nq + 32 * p;
            G0T[(size_t)n * 1024 + m] = acc[i][p] + bih[n] + bhh[n];
        }
    }
}

// ---------------------------------------------------------------------------
// k_u: U[b,s,j] = src[b,s,:] . W_attn[j, 0:512]
// ---------------------------------------------------------------------------
__global__ __launch_bounds__(256) void k_u(const float* __restrict__ src,
                                           const float* __restrict__ Wattn,
                                           float* __restrict__ U) {
    __shared__ float a_s[32][66];
    __shared__ float w_s[32][130];
    const int tid = threadIdx.x;
    const int m0 = blockIdx.x * 64, n0 = blockIdx.y * 128;
    const int mq = tid >> 5, nq = tid & 31;
    float acc[8][4] = {};
    for (int k0 = 0; k0 < 512; k0 += 32) {
        {
            const int mm = tid >> 2, kq = tid & 3, kk = kq * 8;
            const float* row = src + (size_t)(m0 + mm) * 512 + k0 + kk;
            float4 v0 = *(const float4*)(row);
            float4 v1 = *(const float4*)(row + 4);
            a_s[kk + 0][mm] = v0.x; a_s[kk + 1][mm] = v0.y;
            a_s[kk + 2][mm] = v0.z; a_s[kk + 3][mm] = v0.w;
            a_s[kk + 4][mm] = v1.x; a_s[kk + 5][mm] = v1.y;
            a_s[kk + 6][mm] = v1.z; a_s[kk + 7][mm] = v1.w;
        }
        {
            const int nn = tid >> 1, kq = tid & 1, kk = kq * 16;
            const float* row = Wattn + (size_t)(n0 + nn) * 1024 + k0 + kk;
            #pragma unroll
            for (int u = 0; u < 4; u++) {
                float4 v = *(const float4*)(row + u * 4);
                w_s[kk + u * 4 + 0][nn] = v.x; w_s[kk + u * 4 + 1][nn] = v.y;
                w_s[kk + u * 4 + 2][nn] = v.z; w_s[kk + u * 4 + 3][nn] = v.w;
            }
        }
        __syncthreads();
        for (int k = 0; k < 32; k++) {
            float a[8], wv[4];
            #pragma unroll
            for (int i = 0; i < 8; i++) a[i] = a_s[k][mq + 8 * i];
            #pragma unroll
            for (int p = 0; p < 4; p++) wv[p] = w_s[k][nq + 32 * p];
            #pragma unroll
            for (int i = 0; i < 8; i++)
                #pragma unroll
                for (int p = 0; p < 4; p++) acc[i][p] += a[i] * wv[p];
        }
        __syncthreads();
    }
    #pragma unroll
    for (int i = 0; i < 8; i++) {
        const int m = m0 + mq + 8 * i;
        #pragma unroll
        for (int p = 0; p < 4; p++)
            U[(size_t)m * 512 + n0 + nq + 32 * p] = acc[i][p];
    }
}

// ---------------------------------------------------------------------------
// k_tr: WaRT[k][j] = W_attn[j][512+k]
// ---------------------------------------------------------------------------
__global__ __launch_bounds__(256) void k_tr(const float* __restrict__ Wattn,
                                            float* __restrict__ WaRT) {
    __shared__ float t_s[32][33];
    const int tid = threadIdx.x;
    const int bx = blockIdx.x, by = blockIdx.y;
    {
        const int jj = tid >> 3, kq = (tid & 7) * 4;
        float4 v = *(const float4*)(Wattn + (size_t)(by * 32 + jj) * 1024 + 512 + bx * 32 + kq);
        t_s[jj][kq + 0] = v.x; t_s[jj][kq + 1] = v.y;
        t_s[jj][kq + 2] = v.z; t_s[jj][kq + 3] = v.w;
    }
    __syncthreads();
    {
        const int kk = tid >> 3, jq = (tid & 7) * 4;
        float4 w;
        w.x = t_s[jq + 0][kk]; w.y = t_s[jq + 1][kk];
        w.z = t_s[jq + 2][kk]; w.w = t_s[jq + 3][kk];
        *(float4*)(WaRT + (size_t)(bx * 32 + kk) * 512 + by * 32 + jq) = w;
    }
}

// ---------------------------------------------------------------------------
// Persistent scan, 256 blocks x 512 threads (8 waves).
// Block owns LSTM units u0=blk*2, u0+1: gate rows {g*512+u0+ui}, pointwise
// local (c in registers of threads 0..63). Attention: bb=blk&31, p=blk>>5.
// xT: rows 0..511 att (k-major); rows 512+slot*512+u = h, slot=t&1.
// ---------------------------------------------------------------------------
__global__ __launch_bounds__(512) void k_scan(const float* __restrict__ G0T,
                                              const float* __restrict__ U,
                                              const float* __restrict__ WaRT,
                                              const float* __restrict__ Wih,
                                              const float* __restrict__ Whh,
                                              const float* __restrict__ src,
                                              const int* __restrict__ lens,
                                              const float* __restrict__ last_cell,
                                              float* __restrict__ xT,
                                              float* __restrict__ h_b,
                                              float* __restrict__ scb,
                                              float* __restrict__ h_hist,
                                              float* __restrict__ att_hist,
                                              int* __restrict__ bar) {
    __shared__ float Wl[8 * 1024];     // 32 KB: rows {g*512+u0+ui} of [WihA|Whh]
    __shared__ float Ul[200 * 64];     // 51.2 KB U slice for (bb, p)
    __shared__ float red_s[2048];      // 8 KB: per-wave gate partials
    __shared__ float gate_s[256];      // 8 rows x 32 b
    __shared__ float h_s[512];
    __shared__ float al[256];
    __shared__ float pr[512];

    const int blk = blockIdx.x, tid = threadIdx.x;
    const int u0 = blk * 2;
    const int bb = blk & 31, p = blk >> 5;

    // one-time LDS preload: Wl[r][k] : r = g*2+ui -> j = g*512+u0+ui
    for (int f = tid; f < 2048; f += 512) {
        const int r = f >> 8, k = (f & 255) * 4;
        const int j = (r >> 1) * 512 + u0 + (r & 1);
        float4 v;
        if (k < 512) v = *(const float4*)(Wih + (size_t)j * 1024 + 512 + k);
        else         v = *(const float4*)(Whh + (size_t)j * 512 + (k - 512));
        *(float4*)&Wl[r * 1024 + k] = v;
    }
    for (int f = tid; f < 3200; f += 512) {
        const int s = f >> 4, q = (f & 15) * 4;
        *(float4*)&Ul[s * 64 + q] = *(const float4*)(U + ((size_t)bb * S_ + s) * 512 + p * 64 + q);
    }
    float creg = (tid < 64) ? last_cell[(tid & 31) * 512 + u0 + (tid >> 5)] : 0.f;
    __syncthreads();

    const int w = tid >> 6, lane = tid & 63;
    const int hf = lane >> 5, b = lane & 31;
    const int len = lens[bb];

    for (int t = 0; t < T_; t++) {
        // -------- Phase A: gates (K-split over waves/halves) + pointwise ----
        {
            const int hoff = ((t + 1) & 1) * 512;        // slot holding h(t-1)
            const int kbase = w * 128 + hf * 64;
            const float* xp = (kbase < 512)
                ? (xT + (size_t)kbase * 32 + b)
                : (xT + (size_t)(512 + hoff + (kbase - 512)) * 32 + b);
            float acc[8] = {};
            #pragma unroll
            for (int kk = 0; kk < 64; kk += 8) {
                float xv[8];
                #pragma unroll
                for (int i = 0; i < 8; i++)
                    xv[i] = g_load(xp + (size_t)(kk + i) * 32);
                #pragma unroll
                for (int r = 0; r < 8; r++) {
                    const float* wr = &Wl[r * 1024 + kbase + kk];
                    float s0 = xv[0] * wr[0] + xv[1] * wr[1] + xv[2] * wr[2] + xv[3] * wr[3];
                    float s1 = xv[4] * wr[4] + xv[5] * wr[5] + xv[6] * wr[6] + xv[7] * wr[7];
                    acc[r] += s0 + s1;
                }
            }
            #pragma unroll
            for (int r = 0; r < 8; r++) acc[r] += __shfl_xor(acc[r], 32);
            if (hf == 0) {
                #pragma unroll
                for (int r = 0; r < 8; r++) red_s[w * 256 + r * 32 + b] = acc[r];
            }
            __syncthreads();
            if (tid < 256) {
                const int r = tid >> 5, b2 = tid & 31;
                const int j = (r >> 1) * 512 + u0 + (r & 1);
                float g = G0T[(size_t)j * 1024 + t * 32 + b2];
                #pragma unroll
                for (int ww = 0; ww < 8; ww++) g += red_s[ww * 256 + r * 32 + b2];
                gate_s[r * 32 + b2] = g;
            }
            __syncthreads();
            if (tid < 64) {
                const int ui = tid >> 5, b2 = tid & 31, u = u0 + ui;
                const float gi = gate_s[(0 + ui) * 32 + b2];        // r = 0*2+ui
                const float gf = gate_s[(2 + ui) * 32 + b2];        // r = 1*2+ui
                const float gg = gate_s[(4 + ui) * 32 + b2];        // r = 2*2+ui
                const float go = gate_s[(6 + ui) * 32 + b2];        // r = 3*2+ui
                const float cn = sigf(gf) * creg + sigf(gi) * tanhf(gg);
                const float hn = sigf(go) * tanhf(cn);
                creg = cn;
                g_store(&xT[(size_t)(512 + (t & 1) * 512 + u) * 32 + b2], hn);
                g_store(&h_b[b2 * 512 + u], hn);
                h_hist[((size_t)t * B_ + b2) * 512 + u] = hn;
            }
        }
        full_sync(bar, 2 * t);

        // -------- Phase B': scores (h_b -> LDS, 25 s-rows over 8 waves) ----
        {
            h_s[tid] = g_load(&h_b[bb * 512 + tid]);
            __syncthreads();
            for (int i = w; i < 25; i += 8) {
                const int s = p * 25 + i;
                const float* sr = src + ((size_t)bb * S_ + s) * 512;
                const float4 x0 = *(const float4*)(sr + lane * 4);
                const float4 x1 = *(const float4*)(sr + 256 + lane * 4);
                const float4 h0 = *(const float4*)(&h_s[lane * 4]);
                const float4 h1 = *(const float4*)(&h_s[256 + lane * 4]);
                float a = x0.x * h0.x + x0.y * h0.y + x0.z * h0.z + x0.w * h0.w
                        + x1.x * h1.x + x1.y * h1.y + x1.z * h1.z + x1.w * h1.w;
                #pragma unroll
                for (int mk = 1; mk < 64; mk <<= 1) a += __shfl_xor(a, mk);
                if (lane == 0) g_store(&scb[bb * 256 + s], (s < len) ? a : -INFINITY);
            }
        }
        sub_sync(bar, bb, t);

        // -------- Phase C: softmax + att slice ----------------------------
        {
            if (tid < 64) {
                const float v0 = g_load(&scb[bb * 256 + tid]);
                const float v1 = g_load(&scb[bb * 256 + 64 + tid]);
                const float v2 = g_load(&scb[bb * 256 + 128 + tid]);
                const float v3 = (tid < 8) ? g_load(&scb[bb * 256 + 192 + tid]) : -INFINITY;
                float m = fmaxf(fmaxf(v0, v1), fmaxf(v2, v3));
                #pragma unroll
                for (int mk = 1; mk < 64; mk <<= 1) m = fmaxf(m, __shfl_xor(m, mk));
                const float e0 = expf(v0 - m), e1 = expf(v1 - m), e2 = expf(v2 - m);
                const float e3 = (tid < 8) ? expf(v3 - m) : 0.f;
                float sum = (e0 + e1) + (e2 + e3);
                #pragma unroll
                for (int mk = 1; mk < 64; mk <<= 1) sum += __shfl_xor(sum, mk);
                const float inv = 1.f / sum;
                al[tid] = e0 * inv; al[64 + tid] = e1 * inv; al[128 + tid] = e2 * inv;
                if (tid < 8) al[192 + tid] = e3 * inv;
            }
            __syncthreads();
            const int jl = tid & 63, sg = tid >> 6;       // sg 0..7
            float uacc = 0.f;
            #pragma unroll 5
            for (int s = sg * 25; s < sg * 25 + 25; s++)
                uacc += al[s] * Ul[s * 64 + jl];
            const float* wc0 = WaRT + (size_t)(sg * 64) * 512 + p * 64 + jl;
            const float* hp = &h_s[sg * 64];
            float c0 = 0.f, c1 = 0.f;
            #pragma unroll 8
            for (int kk = 0; kk < 64; kk += 2) {
                c0 += hp[kk] * wc0[(size_t)kk * 512];
                c1 += hp[kk + 1] * wc0[(size_t)(kk + 1) * 512];
            }
            pr[tid] = uacc + c0 + c1;
            __syncthreads();
            if (tid < 64) {
                float tot = 0.f;
                #pragma unroll
                for (int sgg = 0; sgg < 8; sgg++) tot += pr[sgg * 64 + tid];
                const float a = tanhf(tot);
                g_store(&xT[(size_t)(p * 64 + tid) * 32 + bb], a);
                att_hist[((size_t)t * B_ + bb) * 512 + p * 64 + tid] = a;
            }
        }
        full_sync(bar, 2 * t + 1);
    }
}

// ---------------------------------------------------------------------------
// k_dec: dh/dl = bf16-split( tanh([emb|h_hist|att_hist] @ Wgen^T + bgen) )
// ---------------------------------------------------------------------------
__global__ __launch_bounds__(256) void k_dec(const int* __restrict__ tgt_in,
                                             const float* __restrict__ emb,
                                             const float* __restrict__ h_hist,
                                             const float* __restrict__ att_hist,
                                             const float* __restrict__ Wgen,
                                             const float* __restrict__ bgen,
                                             unsigned short* __restrict__ dh,
                                             unsigned short* __restrict__ dl) {
    __shared__ float a_s[32][66];
    __shared__ float w_s[32][130];
    const int tid = threadIdx.x;
    const int m0 = blockIdx.x * 64, n0 = blockIdx.y * 128;
    const int mq = tid >> 5, nq = tid & 31;
    float acc[8][4] = {};
    for (int k0 = 0; k0 < 1536; k0 += 32) {
        {
            const int mm = tid >> 2, kq = tid & 3, kk = kq * 8;
            const int m = m0 + mm;
            const float* row;
            if (k0 < 512)       row = emb + (size_t)tgt_in[m] * E_ + k0;
            else if (k0 < 1024) row = h_hist + (size_t)m * 512 + (k0 - 512);
            else                row = att_hist + (size_t)m * 512 + (k0 - 1024);
            row += kk;
            float4 v0 = *(const float4*)(row);
            float4 v1 = *(const float4*)(row + 4);
            a_s[kk + 0][mm] = v0.x; a_s[kk + 1][mm] = v0.y;
            a_s[kk + 2][mm] = v0.z; a_s[kk + 3][mm] = v0.w;
            a_s[kk + 4][mm] = v1.x; a_s[kk + 5][mm] = v1.y;
            a_s[kk + 6][mm] = v1.z; a_s[kk + 7][mm] = v1.w;
        }
        {
            const int nn = tid >> 1, kq = tid & 1, kk = kq * 16;
            const float* row = Wgen + (size_t)(n0 + nn) * 1536 + k0 + kk;
            #pragma unroll
            for (int u = 0; u < 4; u++) {
                float4 v = *(const float4*)(row + u * 4);
                w_s[kk + u * 4 + 0][nn] = v.x; w_s[kk + u * 4 + 1][nn] = v.y;
                w_s[kk + u * 4 + 2][nn] = v.z; w_s[kk + u * 4 + 3][nn] = v.w;
            }
        }
        __syncthreads();
        for (int k = 0; k < 32; k++) {
            float a[8], wv[4];
            #pragma unroll
            for (int i = 0; i < 8; i++) a[i] = a_s[k][mq + 8 * i];
            #pragma unroll
            for (int pq = 0; pq < 4; pq++) wv[pq] = w_s[k][nq + 32 * pq];
            #pragma unroll
            for (int i = 0; i < 8; i++)
                #pragma unroll
                for (int pq = 0; pq < 4; pq++) acc[i][pq] += a[i] * wv[pq];
        }
        __syncthreads();
    }
    #pragma unroll
    for (int i = 0; i < 8; i++) {
        const int m = m0 + mq + 8 * i;
        #pragma unroll
        for (int pq = 0; pq < 4; pq++) {
            const int n = n0 + nq + 32 * pq;
            const float v = tanhf(acc[i][pq] + bgen[n]);
            const unsigned short hb = f2bf(v);
            dh[(size_t)m * 512 + n] = hb;
            dl[(size_t)m * 512 + n] = f2bf(v - bf2f(hb));
        }
    }
}

// ---------------------------------------------------------------------------
// k_read: bf16-split MFMA readout (round-6 version, XCD-grouped grid 3200).
// ---------------------------------------------------------------------------
__global__ __launch_bounds__(256) void k_read(const unsigned short* __restrict__ dh,
                                              const unsigned short* __restrict__ dl,
                                              const float* __restrict__ Wread,
                                              const int* __restrict__ tgt_out,
                                              float4* __restrict__ part,
                                              float* __restrict__ tgt_logit) {
    __shared__ __align__(16) unsigned short Bh[4][256][8];
    __shared__ __align__(16) unsigned short Bl[4][256][8];
    __shared__ __align__(16) unsigned short Ah[4][64][8];
    __shared__ __align__(16) unsigned short Alo[4][64][8];
    __shared__ float ep_max[64][2];
    __shared__ int   ep_idx[64][2];
    __shared__ float ep_fin[64];
    __shared__ int   ep_fidx[64];
    __shared__ float ep_sum[64][2];

    const int xcd = blockIdx.x & 7;
    const int idx = blockIdx.x >> 3;
    const int mi  = idx & 15;
    const int group = idx >> 4;
    const int ch = group * 8 + xcd;
    if (ch >= NCH) return;
    const int m0 = mi * 64, n0 = ch * 256;

    const int tid = threadIdx.x;
    const int lane = tid & 63, wid = tid >> 6;
    const int wr = wid >> 1, wc = wid & 1;
    const int l15 = lane & 15, lk = lane >> 4;

    f32x4 acc[2][8];
    #pragma unroll
    for (int mt = 0; mt < 2; mt++)
        #pragma unroll
        for (int nt = 0; nt < 8; nt++) acc[mt][nt] = {0.f, 0.f, 0.f, 0.f};

    for (int kc = 0; kc < 512; kc += 32) {
        {
            const int n = n0 + tid;
            const float* row = Wread + (size_t)n * 512 + kc;
            #pragma unroll
            for (int g = 0; g < 4; g++) {
                uint4 h4, l4;
                if (n < V_) {
                    float4 p0 = *(const float4*)(row + g * 8);
                    float4 p1 = *(const float4*)(row + g * 8 + 4);
                    float v[8] = {p0.x, p0.y, p0.z, p0.w, p1.x, p1.y, p1.z, p1.w};
                    unsigned int hb[8], lb[8];
                    #pragma unroll
                    for (int e = 0; e < 8; e++) {
                        hb[e] = f2bf(v[e]);
                        lb[e] = f2bf(v[e] - bf2f((unsigned short)hb[e]));
                    }
                    h4 = make_uint4(hb[0] | (hb[1] << 16), hb[2] | (hb[3] << 16),
                                    hb[4] | (hb[5] << 16), hb[6] | (hb[7] << 16));
                    l4 = make_uint4(lb[0] | (lb[1] << 16), lb[2] | (lb[3] << 16),
                                    lb[4] | (lb[5] << 16), lb[6] | (lb[7] << 16));
                } else {
                    h4 = make_uint4(0, 0, 0, 0);
                    l4 = make_uint4(0, 0, 0, 0);
                }
                *(uint4*)&Bh[g][tid][0] = h4;
                *(uint4*)&Bl[g][tid][0] = l4;
            }
        }
        {
            const int row = tid >> 2, g = tid & 3;
            *(uint4*)&Ah[g][row][0]  = *(const uint4*)(dh + (size_t)(m0 + row) * 512 + kc + g * 8);
            *(uint4*)&Alo[g][row][0] = *(const uint4*)(dl + (size_t)(m0 + row) * 512 + kc + g * 8);
        }
        __syncthreads();
        {
            bf16x8 afh[2], afl[2];
            #pragma unroll
            for (int mt = 0; mt < 2; mt++) {
                const int r = wr * 32 + mt * 16 + l15;
                afh[mt] = *(const bf16x8*)&Ah[lk][r][0];
                afl[mt] = *(const bf16x8*)&Alo[lk][r][0];
            }
            #pragma unroll
            for (int nt = 0; nt < 8; nt++) {
                const int nn = wc * 128 + nt * 16 + l15;
                bf16x8 bh = *(const bf16x8*)&Bh[lk][nn][0];
                bf16x8 bl = *(const bf16x8*)&Bl[lk][nn][0];
                #pragma unroll
                for (int mt = 0; mt < 2; mt++) {
                    acc[mt][nt] = __builtin_amdgcn_mfma_f32_16x16x32_bf16(afh[mt], bh, acc[mt][nt], 0, 0, 0);
                    acc[mt][nt] = __builtin_amdgcn_mfma_f32_16x16x32_bf16(afl[mt], bh, acc[mt][nt], 0, 0, 0);
                    acc[mt][nt] = __builtin_amdgcn_mfma_f32_16x16x32_bf16(afh[mt], bl, acc[mt][nt], 0, 0, 0);
                }
            }
        }
        __syncthreads();
    }

    #pragma unroll
    for (int mt = 0; mt < 2; mt++)
        #pragma unroll
        for (int reg = 0; reg < 4; reg++) {
            float bv = -INFINITY; int bi = 0x7fffffff;
            #pragma unroll
            for (int nt = 0; nt < 8; nt++) {
                const int n = n0 + wc * 128 + nt * 16 + l15;
                const float v = (n < V_) ? acc[mt][nt][reg] : -INFINITY;
                if (v > bv || (v == bv && n < bi)) { bv = v; bi = n; }
            }
            #pragma unroll
            for (int mk = 1; mk < 16; mk <<= 1) {
                const float ov = __shfl_xor(bv, mk);
                const int oi = __shfl_xor(bi, mk);
                if (ov > bv || (ov == bv && oi < bi)) { bv = ov; bi = oi; }
            }
            if (l15 == 0) {
                const int rl = wr * 32 + mt * 16 + lk * 4 + reg;
                ep_max[rl][wc] = bv; ep_idx[rl][wc] = bi;
            }
        }
    __syncthreads();
    if (tid < 64) {
        const float a = ep_max[tid][0], b = ep_max[tid][1];
        const int ia = ep_idx[tid][0], ib = ep_idx[tid][1];
        const bool tb = (b > a) || (b == a && ib < ia);
        ep_fin[tid] = tb ? b : a; ep_fidx[tid] = tb ? ib : ia;
    }
    __syncthreads();
    #pragma unroll
    for (int mt = 0; mt < 2; mt++)
        #pragma unroll
        for (int reg = 0; reg < 4; reg++) {
            const int rl = wr * 32 + mt * 16 + lk * 4 + reg;
            const float M = ep_fin[rl];
            const int rel = tgt_out[m0 + rl] - n0;
            float se = 0.f;
            #pragma unroll
            for (int nt = 0; nt < 8; nt++) {
                const int nl = wc * 128 + nt * 16 + l15;
                if (n0 + nl < V_) {
                    const float v = acc[mt][nt][reg];
                    se += expf(v - M);
                    if (nl == rel) tgt_logit[m0 + rl] = v;
                }
            }
            #pragma unroll
            for (int mk = 1; mk < 16; mk <<= 1) se += __shfl_xor(se, mk);
            if (l15 == 0) ep_sum[rl][wc] = se;
        }
    __syncthreads();
    if (tid < 64) {
        part[(size_t)(m0 + tid) * NCH + ch] =
            make_float4(ep_fin[tid], ep_sum[tid][0] + ep_sum[tid][1],
                        __int_as_float(ep_fidx[tid]), 0.f);
    }
}

// ---------------------------------------------------------------------------
// k_merge: combine chunk partials -> loss + argmax
// ---------------------------------------------------------------------------
__global__ __launch_bounds__(256) void k_merge(const float4* __restrict__ part,
                                               const float* __restrict__ tgt_logit,
                                               const int* __restrict__ tgt_out,
                                               float* __restrict__ out) {
    const int tid = threadIdx.x;
    const int w = tid >> 6, lane = tid & 63;
    const int row = blockIdx.x * 4 + w;
    float bm = -INFINITY; int bi = 0x7fffffff;
    for (int ch = lane; ch < NCH; ch += 64) {
        const float4 p = part[(size_t)row * NCH + ch];
        const int pi = __float_as_int(p.z);
        if (p.x > bm || (p.x == bm && pi < bi)) { bm = p.x; bi = pi; }
    }
    #pragma unroll
    for (int mk = 1; mk < 64; mk <<= 1) {
        const float ov = __shfl_xor(bm, mk);
        const int oi = __shfl_xor(bi, mk);
        if (ov > bm || (ov == bm && oi < bi)) { bm = ov; bi = oi; }
    }
    float sum = 0.f;
    for (int ch = lane; ch < NCH; ch += 64) {
        const float4 p = part[(size_t)row * NCH + ch];
        sum += p.y * expf(p.x - bm);
    }
    #pragma unroll
    for (int mk = 1; mk < 64; mk <<= 1) sum += __shfl_xor(sum, mk);
    if (lane == 0) {
        const float lse = bm + logf(sum);
        const int tg = tgt_out[row];
        const float loss = (tg != 0) ? (lse - tgt_logit[row]) : 0.f;
        out[row] = loss;
        out[1024 + row] = (float)bi;
    }
}

// ---------------------------------------------------------------------------
extern "C" void kernel_launch(void* const* d_in, const int* in_sizes, int n_in,
                              void* d_out, int out_size, void* d_ws, size_t ws_size,
                              hipStream_t stream) {
    const int* tgt_in = (const int*)d_in[0];
    const int* tgt_out = (const int*)d_in[1];
    const int* src_lens = (const int*)d_in[2];
    const float* src = (const float*)d_in[3];
    const float* last_state = (const float*)d_in[4];
    const float* last_cell = (const float*)d_in[5];
    const float* emb = (const float*)d_in[6];
    const float* Wih = (const float*)d_in[7];
    const float* Whh = (const float*)d_in[8];
    const float* bih = (const float*)d_in[9];
    const float* bhh = (const float*)d_in[10];
    const float* Wattn = (const float*)d_in[11];
    const float* Wgen = (const float*)d_in[12];
    const float* bgen = (const float*)d_in[13];
    const float* Wread = (const float*)d_in[14];
    float* out = (float*)d_out;

    float* ws = (float*)d_ws;
    float* G0T      = ws;                    // 2,097,152
    float* U        = G0T + 2097152;         // 3,276,800
    float* WaRT     = U + 3276800;           // 262,144
    unsigned short* dh = (unsigned short*)(WaRT + 262144);  // 524,288 u16
    unsigned short* dl = dh + 524288;                       // 524,288 u16
    float* h_hist   = (float*)(dl + 524288); // 524,288
    float* att_hist = h_hist + 524288;       // 524,288
    float* xT       = att_hist + 524288;     // 49,152 (1536 rows x 32)
    float* h_b      = xT + 49152;            // 16,384
    float* scb      = h_b + 16384;           // 8,192
    float4* part    = (float4*)(scb + 8192); // 200,704 float4
    float* tgtl     = ((float*)part) + 802816; // 1,024
    int* bar        = (int*)(tgtl + 1024);     // 2,048 ints

    hipMemsetAsync(bar, 0, 8192, stream);

    k_init<<<64, 256, 0, stream>>>(last_state, xT);
    k_g0<<<dim3(16, 16), 256, 0, stream>>>(tgt_in, emb, Wih, bih, bhh, G0T);
    k_u<<<dim3(100, 4), 256, 0, stream>>>(src, Wattn, U);
    k_tr<<<dim3(16, 16), 256, 0, stream>>>(Wattn, WaRT);

    k_scan<<<256, 512, 0, stream>>>(G0T, U, WaRT, Wih, Whh, src, src_lens, last_cell,
                                    xT, h_b, scb, h_hist, att_hist, bar);

    k_dec<<<dim3(16, 4), 256, 0, stream>>>(tgt_in, emb, h_hist, att_hist, Wgen, bgen, dh, dl);
    k_read<<<3200, 256, 0, stream>>>(dh, dl, Wread, tgt_out, part, tgtl);
    k_merge<<<256, 256, 0, stream>>>(part, tgtl, tgt_out, out);
}

// Round 8
// 1059.696 us; speedup vs baseline: 1.5605x; 1.0723x over previous
//
#include <hip/hip_runtime.h>
#include <math.h>

#define T_ 32
#define B_ 32
#define S_ 200
#define E_ 512
#define H_ 512
#define V_ 50000
#define VP_ 50176   // padded rows for chunk-major bf16 W
#define G4_ 2048
#define NCH 196   // ceil(50000/256)

using bf16x8 = __attribute__((ext_vector_type(8))) __bf16;
using f32x4  = __attribute__((ext_vector_type(4))) float;

__device__ __forceinline__ float sigf(float x) { return 1.f / (1.f + expf(-x)); }

__device__ __forceinline__ unsigned short f2bf(float v) {
    unsigned int x = __float_as_uint(v);
    return (unsigned short)((x + 0x7FFFu + ((x >> 16) & 1u)) >> 16);
}
__device__ __forceinline__ float bf2f(unsigned short b) {
    return __uint_as_float(((unsigned int)b) << 16);
}

// Coherent LLC-level exchange (relaxed agent atomics -> sc1 load/store, no L2 flush)
__device__ __forceinline__ void g_store(float* p, float v) {
    __hip_atomic_store(p, v, __ATOMIC_RELAXED, __HIP_MEMORY_SCOPE_AGENT);
}
__device__ __forceinline__ float g_load(const float* p) {
    return __hip_atomic_load(p, __ATOMIC_RELAXED, __HIP_MEMORY_SCOPE_AGENT);
}

// ---------------------------------------------------------------------------
// Fence-free grid barrier (proven rounds 5-7).
// ---------------------------------------------------------------------------
__device__ __forceinline__ void full_sync(int* bar, int ep) {
    __syncthreads();
    if (threadIdx.x == 0) {
        const int g = blockIdx.x & 7;
        int a = __hip_atomic_fetch_add(&bar[g * 32], 1, __ATOMIC_RELAXED, __HIP_MEMORY_SCOPE_AGENT);
        if (a == ep * 32 + 31) {
            int q = __hip_atomic_fetch_add(&bar[256], 1, __ATOMIC_RELAXED, __HIP_MEMORY_SCOPE_AGENT);
            if (q == ep * 8 + 7) {
                #pragma unroll
                for (int i = 0; i < 8; i++)
                    __hip_atomic_store(&bar[288 + i * 32], ep + 1, __ATOMIC_RELAXED, __HIP_MEMORY_SCOPE_AGENT);
            }
        }
        while (__hip_atomic_load(&bar[288 + g * 32], __ATOMIC_RELAXED, __HIP_MEMORY_SCOPE_AGENT) < ep + 1)
            __builtin_amdgcn_s_sleep(1);
    }
    __syncthreads();
}

__device__ __forceinline__ void sub_sync(int* bar, int bb, int t) {
    __syncthreads();
    if (threadIdx.x == 0) {
        __hip_atomic_fetch_add(&bar[544 + bb * 32], 1, __ATOMIC_RELAXED, __HIP_MEMORY_SCOPE_AGENT);
        while (__hip_atomic_load(&bar[544 + bb * 32], __ATOMIC_RELAXED, __HIP_MEMORY_SCOPE_AGENT) < (t + 1) * 8)
            __builtin_amdgcn_s_sleep(1);
    }
    __syncthreads();
}

// ---------------------------------------------------------------------------
// k_init: xT rows 0..511 att=0; rows 1024..1535 = last_state^T (h slot 1).
// ---------------------------------------------------------------------------
__global__ __launch_bounds__(256) void k_init(const float* __restrict__ last_state,
                                              float* __restrict__ xT) {
    const int f = blockIdx.x * 256 + threadIdx.x;   // 0..16383
    xT[f] = 0.f;
    const int k = f >> 5, b = f & 31;
    xT[32768 + f] = last_state[b * 512 + k];
}

// ---------------------------------------------------------------------------
// k_g0: G0T[j][m] = emb(tgt_in[m]) . W_ih[j][0:512] + b_ih[j] + b_hh[j]
// ---------------------------------------------------------------------------
__global__ __launch_bounds__(256) void k_g0(const int* __restrict__ tgt_in,
                                            const float* __restrict__ emb,
                                            const float* __restrict__ Wih,
                                            const float* __restrict__ bih,
                                            const float* __restrict__ bhh,
                                            float* __restrict__ G0T) {
    __shared__ float a_s[32][66];
    __shared__ float w_s[32][130];
    const int tid = threadIdx.x;
    const int m0 = blockIdx.x * 64, n0 = blockIdx.y * 128;
    const int mq = tid >> 5, nq = tid & 31;
    float acc[8][4] = {};
    for (int k0 = 0; k0 < 512; k0 += 32) {
        {
            const int mm = tid >> 2, kq = tid & 3, kk = kq * 8;
            const float* row = emb + (size_t)tgt_in[m0 + mm] * E_ + k0 + kk;
            float4 v0 = *(const float4*)(row);
            float4 v1 = *(const float4*)(row + 4);
            a_s[kk + 0][mm] = v0.x; a_s[kk + 1][mm] = v0.y;
            a_s[kk + 2][mm] = v0.z; a_s[kk + 3][mm] = v0.w;
            a_s[kk + 4][mm] = v1.x; a_s[kk + 5][mm] = v1.y;
            a_s[kk + 6][mm] = v1.z; a_s[kk + 7][mm] = v1.w;
        }
        {
            const int nn = tid >> 1, kq = tid & 1, kk = kq * 16;
            const float* row = Wih + (size_t)(n0 + nn) * 1024 + k0 + kk;
            #pragma unroll
            for (int u = 0; u < 4; u++) {
                float4 v = *(const float4*)(row + u * 4);
                w_s[kk + u * 4 + 0][nn] = v.x; w_s[kk + u * 4 + 1][nn] = v.y;
                w_s[kk + u * 4 + 2][nn] = v.z; w_s[kk + u * 4 + 3][nn] = v.w;
            }
        }
        __syncthreads();
        for (int k = 0; k < 32; k++) {
            float a[8], wv[4];
            #pragma unroll
            for (int i = 0; i < 8; i++) a[i] = a_s[k][mq + 8 * i];
            #pragma unroll
            for (int p = 0; p < 4; p++) wv[p] = w_s[k][nq + 32 * p];
            #pragma unroll
            for (int i = 0; i < 8; i++)
                #pragma unroll
                for (int p = 0; p < 4; p++) acc[i][p] += a[i] * wv[p];
        }
        __syncthreads();
    }
    #pragma unroll
    for (int i = 0; i < 8; i++) {
        const int m = m0 + mq + 8 * i;
        #pragma unroll
        for (int p = 0; p < 4; p++) {
            const int n = n0 + nq + 32 * p;
            G0T[(size_t)n * 1024 + m] = acc[i][p] + bih[n] + bhh[n];
        }
    }
}

// ---------------------------------------------------------------------------
// k_u: U[b,s,j] = src[b,s,:] . W_attn[j, 0:512]
// ---------------------------------------------------------------------------
__global__ __launch_bounds__(256) void k_u(const float* __restrict__ src,
                                           const float* __restrict__ Wattn,
                                           float* __restrict__ U) {
    __shared__ float a_s[32][66];
    __shared__ float w_s[32][130];
    const int tid = threadIdx.x;
    const int m0 = blockIdx.x * 64, n0 = blockIdx.y * 128;
    const int mq = tid >> 5, nq = tid & 31;
    float acc[8][4] = {};
    for (int k0 = 0; k0 < 512; k0 += 32) {
        {
            const int mm = tid >> 2, kq = tid & 3, kk = kq * 8;
            const float* row = src + (size_t)(m0 + mm) * 512 + k0 + kk;
            float4 v0 = *(const float4*)(row);
            float4 v1 = *(const float4*)(row + 4);
            a_s[kk + 0][mm] = v0.x; a_s[kk + 1][mm] = v0.y;
            a_s[kk + 2][mm] = v0.z; a_s[kk + 3][mm] = v0.w;
            a_s[kk + 4][mm] = v1.x; a_s[kk + 5][mm] = v1.y;
            a_s[kk + 6][mm] = v1.z; a_s[kk + 7][mm] = v1.w;
        }
        {
            const int nn = tid >> 1, kq = tid & 1, kk = kq * 16;
            const float* row = Wattn + (size_t)(n0 + nn) * 1024 + k0 + kk;
            #pragma unroll
            for (int u = 0; u < 4; u++) {
                float4 v = *(const float4*)(row + u * 4);
                w_s[kk + u * 4 + 0][nn] = v.x; w_s[kk + u * 4 + 1][nn] = v.y;
                w_s[kk + u * 4 + 2][nn] = v.z; w_s[kk + u * 4 + 3][nn] = v.w;
            }
        }
        __syncthreads();
        for (int k = 0; k < 32; k++) {
            float a[8], wv[4];
            #pragma unroll
            for (int i = 0; i < 8; i++) a[i] = a_s[k][mq + 8 * i];
            #pragma unroll
            for (int p = 0; p < 4; p++) wv[p] = w_s[k][nq + 32 * p];
            #pragma unroll
            for (int i = 0; i < 8; i++)
                #pragma unroll
                for (int p = 0; p < 4; p++) acc[i][p] += a[i] * wv[p];
        }
        __syncthreads();
    }
    #pragma unroll
    for (int i = 0; i < 8; i++) {
        const int m = m0 + mq + 8 * i;
        #pragma unroll
        for (int p = 0; p < 4; p++)
            U[(size_t)m * 512 + n0 + nq + 32 * p] = acc[i][p];
    }
}

// ---------------------------------------------------------------------------
// k_tr: WaRT[k][j] = W_attn[j][512+k]
// ---------------------------------------------------------------------------
__global__ __launch_bounds__(256) void k_tr(const float* __restrict__ Wattn,
                                            float* __restrict__ WaRT) {
    __shared__ float t_s[32][33];
    const int tid = threadIdx.x;
    const int bx = blockIdx.x, by = blockIdx.y;
    {
        const int jj = tid >> 3, kq = (tid & 7) * 4;
        float4 v = *(const float4*)(Wattn + (size_t)(by * 32 + jj) * 1024 + 512 + bx * 32 + kq);
        t_s[jj][kq + 0] = v.x; t_s[jj][kq + 1] = v.y;
        t_s[jj][kq + 2] = v.z; t_s[jj][kq + 3] = v.w;
    }
    __syncthreads();
    {
        const int kk = tid >> 3, jq = (tid & 7) * 4;
        float4 w;
        w.x = t_s[jq + 0][kk]; w.y = t_s[jq + 1][kk];
        w.z = t_s[jq + 2][kk]; w.w = t_s[jq + 3][kk];
        *(float4*)(WaRT + (size_t)(bx * 32 + kk) * 512 + by * 32 + jq) = w;
    }
}

// ---------------------------------------------------------------------------
// k_wconv: Wread fp32 -> bf16 hi/lo, CHUNK-MAJOR layout:
//   whk[(k>>5)*VP_*32 + n*32 + (k&31)], rows >= V_ zeroed.
// ---------------------------------------------------------------------------
__global__ __launch_bounds__(256) void k_wconv(const float* __restrict__ Wread,
                                               unsigned short* __restrict__ whk,
                                               unsigned short* __restrict__ wlk) {
    const size_t q = (size_t)blockIdx.x * 256 + threadIdx.x;
    const size_t k8 = q * 8;
    const int n = (int)(k8 >> 9);
    const int k = (int)(k8 & 511);
    if (n >= VP_) return;
    uint4 h4, l4;
    if (n < V_) {
        float4 p0 = *(const float4*)(Wread + (size_t)n * 512 + k);
        float4 p1 = *(const float4*)(Wread + (size_t)n * 512 + k + 4);
        float v[8] = {p0.x, p0.y, p0.z, p0.w, p1.x, p1.y, p1.z, p1.w};
        unsigned int hb[8], lb[8];
        #pragma unroll
        for (int e = 0; e < 8; e++) {
            hb[e] = f2bf(v[e]);
            lb[e] = f2bf(v[e] - bf2f((unsigned short)hb[e]));
        }
        h4 = make_uint4(hb[0] | (hb[1] << 16), hb[2] | (hb[3] << 16),
                        hb[4] | (hb[5] << 16), hb[6] | (hb[7] << 16));
        l4 = make_uint4(lb[0] | (lb[1] << 16), lb[2] | (lb[3] << 16),
                        lb[4] | (lb[5] << 16), lb[6] | (lb[7] << 16));
    } else {
        h4 = make_uint4(0, 0, 0, 0);
        l4 = make_uint4(0, 0, 0, 0);
    }
    const size_t dst = (size_t)(k >> 5) * (VP_ * 32) + (size_t)n * 32 + (k & 31);
    *(uint4*)(whk + dst) = h4;
    *(uint4*)(wlk + dst) = l4;
}

// ---------------------------------------------------------------------------
// Persistent scan (round-7 version, unchanged).
// ---------------------------------------------------------------------------
__global__ __launch_bounds__(512) void k_scan(const float* __restrict__ G0T,
                                              const float* __restrict__ U,
                                              const float* __restrict__ WaRT,
                                              const float* __restrict__ Wih,
                                              const float* __restrict__ Whh,
                                              const float* __restrict__ src,
                                              const int* __restrict__ lens,
                                              const float* __restrict__ last_cell,
                                              float* __restrict__ xT,
                                              float* __restrict__ h_b,
                                              float* __restrict__ scb,
                                              float* __restrict__ h_hist,
                                              float* __restrict__ att_hist,
                                              int* __restrict__ bar) {
    __shared__ float Wl[8 * 1024];
    __shared__ float Ul[200 * 64];
    __shared__ float red_s[2048];
    __shared__ float gate_s[256];
    __shared__ float h_s[512];
    __shared__ float al[256];
    __shared__ float pr[512];

    const int blk = blockIdx.x, tid = threadIdx.x;
    const int u0 = blk * 2;
    const int bb = blk & 31, p = blk >> 5;

    for (int f = tid; f < 2048; f += 512) {
        const int r = f >> 8, k = (f & 255) * 4;
        const int j = (r >> 1) * 512 + u0 + (r & 1);
        float4 v;
        if (k < 512) v = *(const float4*)(Wih + (size_t)j * 1024 + 512 + k);
        else         v = *(const float4*)(Whh + (size_t)j * 512 + (k - 512));
        *(float4*)&Wl[r * 1024 + k] = v;
    }
    for (int f = tid; f < 3200; f += 512) {
        const int s = f >> 4, q = (f & 15) * 4;
        *(float4*)&Ul[s * 64 + q] = *(const float4*)(U + ((size_t)bb * S_ + s) * 512 + p * 64 + q);
    }
    float creg = (tid < 64) ? last_cell[(tid & 31) * 512 + u0 + (tid >> 5)] : 0.f;
    __syncthreads();

    const int w = tid >> 6, lane = tid & 63;
    const int hf = lane >> 5, b = lane & 31;
    const int len = lens[bb];

    for (int t = 0; t < T_; t++) {
        {
            const int hoff = ((t + 1) & 1) * 512;
            const int kbase = w * 128 + hf * 64;
            const float* xp = (kbase < 512)
                ? (xT + (size_t)kbase * 32 + b)
                : (xT + (size_t)(512 + hoff + (kbase - 512)) * 32 + b);
            float acc[8] = {};
            #pragma unroll
            for (int kk = 0; kk < 64; kk += 8) {
                float xv[8];
                #pragma unroll
                for (int i = 0; i < 8; i++)
                    xv[i] = g_load(xp + (size_t)(kk + i) * 32);
                #pragma unroll
                for (int r = 0; r < 8; r++) {
                    const float* wr = &Wl[r * 1024 + kbase + kk];
                    float s0 = xv[0] * wr[0] + xv[1] * wr[1] + xv[2] * wr[2] + xv[3] * wr[3];
                    float s1 = xv[4] * wr[4] + xv[5] * wr[5] + xv[6] * wr[6] + xv[7] * wr[7];
                    acc[r] += s0 + s1;
                }
            }
            #pragma unroll
            for (int r = 0; r < 8; r++) acc[r] += __shfl_xor(acc[r], 32);
            if (hf == 0) {
                #pragma unroll
                for (int r = 0; r < 8; r++) red_s[w * 256 + r * 32 + b] = acc[r];
            }
            __syncthreads();
            if (tid < 256) {
                const int r = tid >> 5, b2 = tid & 31;
                const int j = (r >> 1) * 512 + u0 + (r & 1);
                float g = G0T[(size_t)j * 1024 + t * 32 + b2];
                #pragma unroll
                for (int ww = 0; ww < 8; ww++) g += red_s[ww * 256 + r * 32 + b2];
                gate_s[r * 32 + b2] = g;
            }
            __syncthreads();
            if (tid < 64) {
                const int ui = tid >> 5, b2 = tid & 31, u = u0 + ui;
                const float gi = gate_s[(0 + ui) * 32 + b2];
                const float gf = gate_s[(2 + ui) * 32 + b2];
                const float gg = gate_s[(4 + ui) * 32 + b2];
                const float go = gate_s[(6 + ui) * 32 + b2];
                const float cn = sigf(gf) * creg + sigf(gi) * tanhf(gg);
                const float hn = sigf(go) * tanhf(cn);
                creg = cn;
                g_store(&xT[(size_t)(512 + (t & 1) * 512 + u) * 32 + b2], hn);
                g_store(&h_b[b2 * 512 + u], hn);
                h_hist[((size_t)t * B_ + b2) * 512 + u] = hn;
            }
        }
        full_sync(bar, 2 * t);

        {
            h_s[tid] = g_load(&h_b[bb * 512 + tid]);
            __syncthreads();
            for (int i = w; i < 25; i += 8) {
                const int s = p * 25 + i;
                const float* sr = src + ((size_t)bb * S_ + s) * 512;
                const float4 x0 = *(const float4*)(sr + lane * 4);
                const float4 x1 = *(const float4*)(sr + 256 + lane * 4);
                const float4 h0 = *(const float4*)(&h_s[lane * 4]);
                const float4 h1 = *(const float4*)(&h_s[256 + lane * 4]);
                float a = x0.x * h0.x + x0.y * h0.y + x0.z * h0.z + x0.w * h0.w
                        + x1.x * h1.x + x1.y * h1.y + x1.z * h1.z + x1.w * h1.w;
                #pragma unroll
                for (int mk = 1; mk < 64; mk <<= 1) a += __shfl_xor(a, mk);
                if (lane == 0) g_store(&scb[bb * 256 + s], (s < len) ? a : -INFINITY);
            }
        }
        sub_sync(bar, bb, t);

        {
            if (tid < 64) {
                const float v0 = g_load(&scb[bb * 256 + tid]);
                const float v1 = g_load(&scb[bb * 256 + 64 + tid]);
                const float v2 = g_load(&scb[bb * 256 + 128 + tid]);
                const float v3 = (tid < 8) ? g_load(&scb[bb * 256 + 192 + tid]) : -INFINITY;
                float m = fmaxf(fmaxf(v0, v1), fmaxf(v2, v3));
                #pragma unroll
                for (int mk = 1; mk < 64; mk <<= 1) m = fmaxf(m, __shfl_xor(m, mk));
                const float e0 = expf(v0 - m), e1 = expf(v1 - m), e2 = expf(v2 - m);
                const float e3 = (tid < 8) ? expf(v3 - m) : 0.f;
                float sum = (e0 + e1) + (e2 + e3);
                #pragma unroll
                for (int mk = 1; mk < 64; mk <<= 1) sum += __shfl_xor(sum, mk);
                const float inv = 1.f / sum;
                al[tid] = e0 * inv; al[64 + tid] = e1 * inv; al[128 + tid] = e2 * inv;
                if (tid < 8) al[192 + tid] = e3 * inv;
            }
            __syncthreads();
            const int jl = tid & 63, sg = tid >> 6;
            float uacc = 0.f;
            #pragma unroll 5
            for (int s = sg * 25; s < sg * 25 + 25; s++)
                uacc += al[s] * Ul[s * 64 + jl];
            const float* wc0 = WaRT + (size_t)(sg * 64) * 512 + p * 64 + jl;
            const float* hp = &h_s[sg * 64];
            float c0 = 0.f, c1 = 0.f;
            #pragma unroll 8
            for (int kk = 0; kk < 64; kk += 2) {
                c0 += hp[kk] * wc0[(size_t)kk * 512];
                c1 += hp[kk + 1] * wc0[(size_t)(kk + 1) * 512];
            }
            pr[tid] = uacc + c0 + c1;
            __syncthreads();
            if (tid < 64) {
                float tot = 0.f;
                #pragma unroll
                for (int sgg = 0; sgg < 8; sgg++) tot += pr[sgg * 64 + tid];
                const float a = tanhf(tot);
                g_store(&xT[(size_t)(p * 64 + tid) * 32 + bb], a);
                att_hist[((size_t)t * B_ + bb) * 512 + p * 64 + tid] = a;
            }
        }
        full_sync(bar, 2 * t + 1);
    }
}

// ---------------------------------------------------------------------------
// k_dec: dh/dl = bf16-split( tanh([emb|h_hist|att_hist] @ Wgen^T + bgen) )
// ---------------------------------------------------------------------------
__global__ __launch_bounds__(256) void k_dec(const int* __restrict__ tgt_in,
                                             const float* __restrict__ emb,
                                             const float* __restrict__ h_hist,
                                             const float* __restrict__ att_hist,
                                             const float* __restrict__ Wgen,
                                             const float* __restrict__ bgen,
                                             unsigned short* __restrict__ dh,
                                             unsigned short* __restrict__ dl) {
    __shared__ float a_s[32][66];
    __shared__ float w_s[32][130];
    const int tid = threadIdx.x;
    const int m0 = blockIdx.x * 64, n0 = blockIdx.y * 128;
    const int mq = tid >> 5, nq = tid & 31;
    float acc[8][4] = {};
    for (int k0 = 0; k0 < 1536; k0 += 32) {
        {
            const int mm = tid >> 2, kq = tid & 3, kk = kq * 8;
            const int m = m0 + mm;
            const float* row;
            if (k0 < 512)       row = emb + (size_t)tgt_in[m] * E_ + k0;
            else if (k0 < 1024) row = h_hist + (size_t)m * 512 + (k0 - 512);
            else                row = att_hist + (size_t)m * 512 + (k0 - 1024);
            row += kk;
            float4 v0 = *(const float4*)(row);
            float4 v1 = *(const float4*)(row + 4);
            a_s[kk + 0][mm] = v0.x; a_s[kk + 1][mm] = v0.y;
            a_s[kk + 2][mm] = v0.z; a_s[kk + 3][mm] = v0.w;
            a_s[kk + 4][mm] = v1.x; a_s[kk + 5][mm] = v1.y;
            a_s[kk + 6][mm] = v1.z; a_s[kk + 7][mm] = v1.w;
        }
        {
            const int nn = tid >> 1, kq = tid & 1, kk = kq * 16;
            const float* row = Wgen + (size_t)(n0 + nn) * 1536 + k0 + kk;
            #pragma unroll
            for (int u = 0; u < 4; u++) {
                float4 v = *(const float4*)(row + u * 4);
                w_s[kk + u * 4 + 0][nn] = v.x; w_s[kk + u * 4 + 1][nn] = v.y;
                w_s[kk + u * 4 + 2][nn] = v.z; w_s[kk + u * 4 + 3][nn] = v.w;
            }
        }
        __syncthreads();
        for (int k = 0; k < 32; k++) {
            float a[8], wv[4];
            #pragma unroll
            for (int i = 0; i < 8; i++) a[i] = a_s[k][mq + 8 * i];
            #pragma unroll
            for (int pq = 0; pq < 4; pq++) wv[pq] = w_s[k][nq + 32 * pq];
            #pragma unroll
            for (int i = 0; i < 8; i++)
                #pragma unroll
                for (int pq = 0; pq < 4; pq++) acc[i][pq] += a[i] * wv[pq];
        }
        __syncthreads();
    }
    #pragma unroll
    for (int i = 0; i < 8; i++) {
        const int m = m0 + mq + 8 * i;
        #pragma unroll
        for (int pq = 0; pq < 4; pq++) {
            const int n = n0 + nq + 32 * pq;
            const float v = tanhf(acc[i][pq] + bgen[n]);
            const unsigned short hb = f2bf(v);
            dh[(size_t)m * 512 + n] = hb;
            dl[(size_t)m * 512 + n] = f2bf(v - bf2f(hb));
        }
    }
}

// ===========================================================================
// k_read_pre: MFMA readout with PRECONVERTED chunk-major bf16 W (no in-kernel
// conversion; fully coalesced staging). Grid 3200, XCD-grouped.
// ===========================================================================
__global__ __launch_bounds__(256) void k_read_pre(const unsigned short* __restrict__ dh,
                                                  const unsigned short* __restrict__ dl,
                                                  const unsigned short* __restrict__ whk,
                                                  const unsigned short* __restrict__ wlk,
                                                  const int* __restrict__ tgt_out,
                                                  float4* __restrict__ part,
                                                  float* __restrict__ tgt_logit) {
    __shared__ __align__(16) unsigned short Bh[4][256][8];
    __shared__ __align__(16) unsigned short Bl[4][256][8];
    __shared__ __align__(16) unsigned short Ah[4][64][8];
    __shared__ __align__(16) unsigned short Alo[4][64][8];
    __shared__ float ep_max[64][2];
    __shared__ int   ep_idx[64][2];
    __shared__ float ep_fin[64];
    __shared__ int   ep_fidx[64];
    __shared__ float ep_sum[64][2];

    const int xcd = blockIdx.x & 7;
    const int idx = blockIdx.x >> 3;
    const int mi  = idx & 15;
    const int group = idx >> 4;
    const int ch = group * 8 + xcd;
    if (ch >= NCH) return;
    const int m0 = mi * 64, n0 = ch * 256;

    const int tid = threadIdx.x;
    const int lane = tid & 63, wid = tid >> 6;
    const int wr = wid >> 1, wc = wid & 1;
    const int l15 = lane & 15, lk = lane >> 4;
    const int srow = tid >> 2, sg = tid & 3;

    f32x4 acc[2][8];
    #pragma unroll
    for (int mt = 0; mt < 2; mt++)
        #pragma unroll
        for (int nt = 0; nt < 8; nt++) acc[mt][nt] = {0.f, 0.f, 0.f, 0.f};

    for (int kc = 0; kc < 512; kc += 32) {
        {   // B stage: contiguous 16 KB per array, 1 KB/wave-instr
            const size_t cb = (size_t)(kc >> 5) * ((size_t)VP_ * 32) + (size_t)n0 * 32;
            const unsigned short* ph = whk + cb;
            const unsigned short* pl = wlk + cb;
            #pragma unroll
            for (int i = 0; i < 4; i++) {
                const int e = i * 2048 + tid * 8;
                uint4 h4 = *(const uint4*)(ph + e);
                uint4 l4 = *(const uint4*)(pl + e);
                const int row = i * 64 + (tid >> 2), g = tid & 3;
                *(uint4*)&Bh[g][row][0] = h4;
                *(uint4*)&Bl[g][row][0] = l4;
            }
        }
        {   // A stage
            *(uint4*)&Ah[sg][srow][0]  = *(const uint4*)(dh + (size_t)(m0 + srow) * 512 + kc + sg * 8);
            *(uint4*)&Alo[sg][srow][0] = *(const uint4*)(dl + (size_t)(m0 + srow) * 512 + kc + sg * 8);
        }
        __syncthreads();
        {
            bf16x8 afh[2], afl[2];
            #pragma unroll
            for (int mt = 0; mt < 2; mt++) {
                const int r = wr * 32 + mt * 16 + l15;
                afh[mt] = *(const bf16x8*)&Ah[lk][r][0];
                afl[mt] = *(const bf16x8*)&Alo[lk][r][0];
            }
            #pragma unroll
            for (int nt = 0; nt < 8; nt++) {
                const int nn = wc * 128 + nt * 16 + l15;
                bf16x8 bh = *(const bf16x8*)&Bh[lk][nn][0];
                bf16x8 bl = *(const bf16x8*)&Bl[lk][nn][0];
                #pragma unroll
                for (int mt = 0; mt < 2; mt++) {
                    acc[mt][nt] = __builtin_amdgcn_mfma_f32_16x16x32_bf16(afh[mt], bh, acc[mt][nt], 0, 0, 0);
                    acc[mt][nt] = __builtin_amdgcn_mfma_f32_16x16x32_bf16(afl[mt], bh, acc[mt][nt], 0, 0, 0);
                    acc[mt][nt] = __builtin_amdgcn_mfma_f32_16x16x32_bf16(afh[mt], bl, acc[mt][nt], 0, 0, 0);
                }
            }
        }
        __syncthreads();
    }

    #pragma unroll
    for (int mt = 0; mt < 2; mt++)
        #pragma unroll
        for (int reg = 0; reg < 4; reg++) {
            float bv = -INFINITY; int bi = 0x7fffffff;
            #pragma unroll
            for (int nt = 0; nt < 8; nt++) {
                const int n = n0 + wc * 128 + nt * 16 + l15;
                const float v = (n < V_) ? acc[mt][nt][reg] : -INFINITY;
                if (v > bv || (v == bv && n < bi)) { bv = v; bi = n; }
            }
            #pragma unroll
            for (int mk = 1; mk < 16; mk <<= 1) {
                const float ov = __shfl_xor(bv, mk);
                const int oi = __shfl_xor(bi, mk);
                if (ov > bv || (ov == bv && oi < bi)) { bv = ov; bi = oi; }
            }
            if (l15 == 0) {
                const int rl = wr * 32 + mt * 16 + lk * 4 + reg;
                ep_max[rl][wc] = bv; ep_idx[rl][wc] = bi;
            }
        }
    __syncthreads();
    if (tid < 64) {
        const float a = ep_max[tid][0], b = ep_max[tid][1];
        const int ia = ep_idx[tid][0], ib = ep_idx[tid][1];
        const bool tb = (b > a) || (b == a && ib < ia);
        ep_fin[tid] = tb ? b : a; ep_fidx[tid] = tb ? ib : ia;
    }
    __syncthreads();
    #pragma unroll
    for (int mt = 0; mt < 2; mt++)
        #pragma unroll
        for (int reg = 0; reg < 4; reg++) {
            const int rl = wr * 32 + mt * 16 + lk * 4 + reg;
            const float M = ep_fin[rl];
            const int rel = tgt_out[m0 + rl] - n0;
            float se = 0.f;
            #pragma unroll
            for (int nt = 0; nt < 8; nt++) {
                const int nl = wc * 128 + nt * 16 + l15;
                if (n0 + nl < V_) {
                    const float v = acc[mt][nt][reg];
                    se += expf(v - M);
                    if (nl == rel) tgt_logit[m0 + rl] = v;
                }
            }
            #pragma unroll
            for (int mk = 1; mk < 16; mk <<= 1) se += __shfl_xor(se, mk);
            if (l15 == 0) ep_sum[rl][wc] = se;
        }
    __syncthreads();
    if (tid < 64) {
        part[(size_t)(m0 + tid) * NCH + ch] =
            make_float4(ep_fin[tid], ep_sum[tid][0] + ep_sum[tid][1],
                        __int_as_float(ep_fidx[tid]), 0.f);
    }
}

// ---------------------------------------------------------------------------
// k_read (fallback, round-7 version with in-kernel conversion)
// ---------------------------------------------------------------------------
__global__ __launch_bounds__(256) void k_read(const unsigned short* __restrict__ dh,
                                              const unsigned short* __restrict__ dl,
                                              const float* __restrict__ Wread,
                                              const int* __restrict__ tgt_out,
                                              float4* __restrict__ part,
                                              float* __restrict__ tgt_logit) {
    __shared__ __align__(16) unsigned short Bh[4][256][8];
    __shared__ __align__(16) unsigned short Bl[4][256][8];
    __shared__ __align__(16) unsigned short Ah[4][64][8];
    __shared__ __align__(16) unsigned short Alo[4][64][8];
    __shared__ float ep_max[64][2];
    __shared__ int   ep_idx[64][2];
    __shared__ float ep_fin[64];
    __shared__ int   ep_fidx[64];
    __shared__ float ep_sum[64][2];

    const int xcd = blockIdx.x & 7;
    const int idx = blockIdx.x >> 3;
    const int mi  = idx & 15;
    const int group = idx >> 4;
    const int ch = group * 8 + xcd;
    if (ch >= NCH) return;
    const int m0 = mi * 64, n0 = ch * 256;

    const int tid = threadIdx.x;
    const int lane = tid & 63, wid = tid >> 6;
    const int wr = wid >> 1, wc = wid & 1;
    const int l15 = lane & 15, lk = lane >> 4;

    f32x4 acc[2][8];
    #pragma unroll
    for (int mt = 0; mt < 2; mt++)
        #pragma unroll
        for (int nt = 0; nt < 8; nt++) acc[mt][nt] = {0.f, 0.f, 0.f, 0.f};

    for (int kc = 0; kc < 512; kc += 32) {
        {
            const int n = n0 + tid;
            const float* row = Wread + (size_t)n * 512 + kc;
            #pragma unroll
            for (int g = 0; g < 4; g++) {
                uint4 h4, l4;
                if (n < V_) {
                    float4 p0 = *(const float4*)(row + g * 8);
                    float4 p1 = *(const float4*)(row + g * 8 + 4);
                    float v[8] = {p0.x, p0.y, p0.z, p0.w, p1.x, p1.y, p1.z, p1.w};
                    unsigned int hb[8], lb[8];
                    #pragma unroll
                    for (int e = 0; e < 8; e++) {
                        hb[e] = f2bf(v[e]);
                        lb[e] = f2bf(v[e] - bf2f((unsigned short)hb[e]));
                    }
                    h4 = make_uint4(hb[0] | (hb[1] << 16), hb[2] | (hb[3] << 16),
                                    hb[4] | (hb[5] << 16), hb[6] | (hb[7] << 16));
                    l4 = make_uint4(lb[0] | (lb[1] << 16), lb[2] | (lb[3] << 16),
                                    lb[4] | (lb[5] << 16), lb[6] | (lb[7] << 16));
                } else {
                    h4 = make_uint4(0, 0, 0, 0);
                    l4 = make_uint4(0, 0, 0, 0);
                }
                *(uint4*)&Bh[g][tid][0] = h4;
                *(uint4*)&Bl[g][tid][0] = l4;
            }
        }
        {
            const int row = tid >> 2, g = tid & 3;
            *(uint4*)&Ah[g][row][0]  = *(const uint4*)(dh + (size_t)(m0 + row) * 512 + kc + g * 8);
            *(uint4*)&Alo[g][row][0] = *(const uint4*)(dl + (size_t)(m0 + row) * 512 + kc + g * 8);
        }
        __syncthreads();
        {
            bf16x8 afh[2], afl[2];
            #pragma unroll
            for (int mt = 0; mt < 2; mt++) {
                const int r = wr * 32 + mt * 16 + l15;
                afh[mt] = *(const bf16x8*)&Ah[lk][r][0];
                afl[mt] = *(const bf16x8*)&Alo[lk][r][0];
            }
            #pragma unroll
            for (int nt = 0; nt < 8; nt++) {
                const int nn = wc * 128 + nt * 16 + l15;
                bf16x8 bh = *(const bf16x8*)&Bh[lk][nn][0];
                bf16x8 bl = *(const bf16x8*)&Bl[lk][nn][0];
                #pragma unroll
                for (int mt = 0; mt < 2; mt++) {
                    acc[mt][nt] = __builtin_amdgcn_mfma_f32_16x16x32_bf16(afh[mt], bh, acc[mt][nt], 0, 0, 0);
                    acc[mt][nt] = __builtin_amdgcn_mfma_f32_16x16x32_bf16(afl[mt], bh, acc[mt][nt], 0, 0, 0);
                    acc[mt][nt] = __builtin_amdgcn_mfma_f32_16x16x32_bf16(afh[mt], bl, acc[mt][nt], 0, 0, 0);
                }
            }
        }
        __syncthreads();
    }

    #pragma unroll
    for (int mt = 0; mt < 2; mt++)
        #pragma unroll
        for (int reg = 0; reg < 4; reg++) {
            float bv = -INFINITY; int bi = 0x7fffffff;
            #pragma unroll
            for (int nt = 0; nt < 8; nt++) {
                const int n = n0 + wc * 128 + nt * 16 + l15;
                const float v = (n < V_) ? acc[mt][nt][reg] : -INFINITY;
                if (v > bv || (v == bv && n < bi)) { bv = v; bi = n; }
            }
            #pragma unroll
            for (int mk = 1; mk < 16; mk <<= 1) {
                const float ov = __shfl_xor(bv, mk);
                const int oi = __shfl_xor(bi, mk);
                if (ov > bv || (ov == bv && oi < bi)) { bv = ov; bi = oi; }
            }
            if (l15 == 0) {
                const int rl = wr * 32 + mt * 16 + lk * 4 + reg;
                ep_max[rl][wc] = bv; ep_idx[rl][wc] = bi;
            }
        }
    __syncthreads();
    if (tid < 64) {
        const float a = ep_max[tid][0], b = ep_max[tid][1];
        const int ia = ep_idx[tid][0], ib = ep_idx[tid][1];
        const bool tb = (b > a) || (b == a && ib < ia);
        ep_fin[tid] = tb ? b : a; ep_fidx[tid] = tb ? ib : ia;
    }
    __syncthreads();
    #pragma unroll
    for (int mt = 0; mt < 2; mt++)
        #pragma unroll
        for (int reg = 0; reg < 4; reg++) {
            const int rl = wr * 32 + mt * 16 + lk * 4 + reg;
            const float M = ep_fin[rl];
            const int rel = tgt_out[m0 + rl] - n0;
            float se = 0.f;
            #pragma unroll
            for (int nt = 0; nt < 8; nt++) {
                const int nl = wc * 128 + nt * 16 + l15;
                if (n0 + nl < V_) {
                    const float v = acc[mt][nt][reg];
                    se += expf(v - M);
                    if (nl == rel) tgt_logit[m0 + rl] = v;
                }
            }
            #pragma unroll
            for (int mk = 1; mk < 16; mk <<= 1) se += __shfl_xor(se, mk);
            if (l15 == 0) ep_sum[rl][wc] = se;
        }
    __syncthreads();
    if (tid < 64) {
        part[(size_t)(m0 + tid) * NCH + ch] =
            make_float4(ep_fin[tid], ep_sum[tid][0] + ep_sum[tid][1],
                        __int_as_float(ep_fidx[tid]), 0.f);
    }
}

// ---------------------------------------------------------------------------
// k_merge: combine chunk partials -> loss + argmax
// ---------------------------------------------------------------------------
__global__ __launch_bounds__(256) void k_merge(const float4* __restrict__ part,
                                               const float* __restrict__ tgt_logit,
                                               const int* __restrict__ tgt_out,
                                               float* __restrict__ out) {
    const int tid = threadIdx.x;
    const int w = tid >> 6, lane = tid & 63;
    const int row = blockIdx.x * 4 + w;
    float bm = -INFINITY; int bi = 0x7fffffff;
    for (int ch = lane; ch < NCH; ch += 64) {
        const float4 p = part[(size_t)row * NCH + ch];
        const int pi = __float_as_int(p.z);
        if (p.x > bm || (p.x == bm && pi < bi)) { bm = p.x; bi = pi; }
    }
    #pragma unroll
    for (int mk = 1; mk < 64; mk <<= 1) {
        const float ov = __shfl_xor(bm, mk);
        const int oi = __shfl_xor(bi, mk);
        if (ov > bm || (ov == bm && oi < bi)) { bm = ov; bi = oi; }
    }
    float sum = 0.f;
    for (int ch = lane; ch < NCH; ch += 64) {
        const float4 p = part[(size_t)row * NCH + ch];
        sum += p.y * expf(p.x - bm);
    }
    #pragma unroll
    for (int mk = 1; mk < 64; mk <<= 1) sum += __shfl_xor(sum, mk);
    if (lane == 0) {
        const float lse = bm + logf(sum);
        const int tg = tgt_out[row];
        const float loss = (tg != 0) ? (lse - tgt_logit[row]) : 0.f;
        out[row] = loss;
        out[1024 + row] = (float)bi;
    }
}

// ---------------------------------------------------------------------------
extern "C" void kernel_launch(void* const* d_in, const int* in_sizes, int n_in,
                              void* d_out, int out_size, void* d_ws, size_t ws_size,
                              hipStream_t stream) {
    const int* tgt_in = (const int*)d_in[0];
    const int* tgt_out = (const int*)d_in[1];
    const int* src_lens = (const int*)d_in[2];
    const float* src = (const float*)d_in[3];
    const float* last_state = (const float*)d_in[4];
    const float* last_cell = (const float*)d_in[5];
    const float* emb = (const float*)d_in[6];
    const float* Wih = (const float*)d_in[7];
    const float* Whh = (const float*)d_in[8];
    const float* bih = (const float*)d_in[9];
    const float* bhh = (const float*)d_in[10];
    const float* Wattn = (const float*)d_in[11];
    const float* Wgen = (const float*)d_in[12];
    const float* bgen = (const float*)d_in[13];
    const float* Wread = (const float*)d_in[14];
    float* out = (float*)d_out;

    float* ws = (float*)d_ws;
    float* G0T      = ws;                    // 2,097,152
    float* U        = G0T + 2097152;         // 3,276,800
    float* WaRT     = U + 3276800;           // 262,144
    unsigned short* dh = (unsigned short*)(WaRT + 262144);  // 524,288 u16
    unsigned short* dl = dh + 524288;                       // 524,288 u16
    float* h_hist   = (float*)(dl + 524288); // 524,288
    float* att_hist = h_hist + 524288;       // 524,288
    float* xT       = att_hist + 524288;     // 49,152
    float* h_b      = xT + 49152;            // 16,384
    float* scb      = h_b + 16384;           // 8,192
    float4* part    = (float4*)(scb + 8192); // 200,704 float4
    float* tgtl     = ((float*)part) + 802816; // 1,024
    int* bar        = (int*)(tgtl + 1024);     // 2,048 ints
    unsigned short* whk = (unsigned short*)(bar + 2048);   // VP_*512 u16
    unsigned short* wlk = whk + (size_t)VP_ * 512;         // VP_*512 u16

    const size_t need = ((size_t)((float*)whk - ws) + (size_t)VP_ * 512) * 4;
    const bool pre = (ws_size >= need);

    hipMemsetAsync(bar, 0, 8192, stream);

    k_init<<<64, 256, 0, stream>>>(last_state, xT);
    k_g0<<<dim3(16, 16), 256, 0, stream>>>(tgt_in, emb, Wih, bih, bhh, G0T);
    k_u<<<dim3(100, 4), 256, 0, stream>>>(src, Wattn, U);
    k_tr<<<dim3(16, 16), 256, 0, stream>>>(Wattn, WaRT);
    if (pre)
        k_wconv<<<12544, 256, 0, stream>>>(Wread, whk, wlk);

    k_scan<<<256, 512, 0, stream>>>(G0T, U, WaRT, Wih, Whh, src, src_lens, last_cell,
                                    xT, h_b, scb, h_hist, att_hist, bar);

    k_dec<<<dim3(16, 4), 256, 0, stream>>>(tgt_in, emb, h_hist, att_hist, Wgen, bgen, dh, dl);
    if (pre)
        k_read_pre<<<3200, 256, 0, stream>>>(dh, dl, whk, wlk, tgt_out, part, tgtl);
    else
        k_read<<<3200, 256, 0, stream>>>(dh, dl, Wread, tgt_out, part, tgtl);
    k_merge<<<256, 256, 0, stream>>>(part, tgtl, tgt_out, out);
}